// Round 1
// baseline (1629.799 us; speedup 1.0000x reference)
//
#include <hip/hip_runtime.h>
#include <cmath>

// ---------------------------------------------------------------------------
// OHDeltaProductSSM: u(8,2048,1024) -> out(8,2048,1024), fp32.
// Pipeline:
//   packW  : gather all weight rows into Wp[512][1024] (+bias[512])
//   gemmA  : Feat_raw[t][0..512) = u[t] . Wp[n]   (fp32 tiled GEMM)
//   postA  : per-token nonlinearity: S, C1=DT*A*S, normalized k1/k2, beta,
//            Bt, c12=k1.k2   (in-place in Feat, stride FS=520)
//   scanB1 : per (batch,chunk of 64 steps): evolve 128 unit columns + d
//            column -> chunk transition M_c (128x128) and offset d_c.
//            One column per thread => dots are thread-local (no reductions).
//   scanB2 : sequential combine over 32 chunks/batch: h <- M_c h + d_c,
//            records h at each chunk start.
//   scanB3 : replay each chunk (1 wave, 64 steps) from its h_start, writing
//            all per-token states hs[t][128].
//   gemmC  : out[t][d] = hs[t] . C[d] + u[t][d]*D[d]
// Feat layout per token (FS=520 floats):
//   [0,64)=S  [64,192)=k1  [192,320)=k2  [320]=b1 [321]=b2
//   [322,450)=Bt  [450,514)=C1  [514]=c12
// ---------------------------------------------------------------------------

#define NTOK 16384
#define TT 2048
#define BB 8
#define DM 1024
#define FS 520
#define CH 32
#define LCH 64

__global__ __launch_bounds__(256) void packW(
    const float* __restrict__ W_A, const float* __restrict__ b_A,
    const float* __restrict__ W_k, const float* __restrict__ b_k,
    const float* __restrict__ W_beta, const float* __restrict__ b_beta,
    const float* __restrict__ B_w, const float* __restrict__ B_b,
    float* __restrict__ Wp, float* __restrict__ bias) {
  int r = blockIdx.x;          // 0..511
  int tid = threadIdx.x;       // 256 threads, one float4 each (1024 floats/row)
  const float* src = nullptr;
  float bv = 0.f;
  if (r < 64)       { src = W_A    + (size_t)r * DM;       bv = b_A[r]; }
  else if (r < 320) { src = W_k    + (size_t)(r - 64) * DM; bv = b_k[r - 64]; }
  else if (r < 322) { src = W_beta + (size_t)(r - 320) * DM; bv = b_beta[r - 320]; }
  else if (r < 450) { src = B_w    + (size_t)(r - 322) * DM; bv = B_b[r - 322]; }
  float4* dst = (float4*)(Wp + (size_t)r * DM);
  if (src) dst[tid] = ((const float4*)src)[tid];
  else     dst[tid] = make_float4(0.f, 0.f, 0.f, 0.f);
  if (tid == 0) bias[r] = bv;
}

// Feat_raw = u @ Wp^T : tile 128 tokens x 64 feats, BK=32
__global__ __launch_bounds__(256) void gemmA(
    const float* __restrict__ u, const float* __restrict__ Wp,
    float* __restrict__ Feat) {
  __shared__ float us[32][132];   // [k][m], stride 132 floats (528B, 16B mult)
  __shared__ float wsm[32][68];   // [k][n]
  const int tid = threadIdx.x;
  const int tx = tid & 15, ty = tid >> 4;
  const int m0 = blockIdx.x * 128;
  const int n0 = blockIdx.y * 64;
  float acc[8][4];
#pragma unroll
  for (int i = 0; i < 8; ++i)
#pragma unroll
    for (int j = 0; j < 4; ++j) acc[i][j] = 0.f;

  for (int k0 = 0; k0 < DM; k0 += 32) {
#pragma unroll
    for (int l = 0; l < 4; ++l) {        // u tile: 128x32
      int idx = tid + l * 256;
      int r = idx >> 3, c = (idx & 7) * 4;
      float4 v = *(const float4*)(u + (size_t)(m0 + r) * DM + k0 + c);
      us[c + 0][r] = v.x; us[c + 1][r] = v.y; us[c + 2][r] = v.z; us[c + 3][r] = v.w;
    }
#pragma unroll
    for (int l = 0; l < 2; ++l) {        // W tile: 64x32
      int idx = tid + l * 256;
      int r = idx >> 3, c = (idx & 7) * 4;
      float4 v = *(const float4*)(Wp + (size_t)(n0 + r) * DM + k0 + c);
      wsm[c + 0][r] = v.x; wsm[c + 1][r] = v.y; wsm[c + 2][r] = v.z; wsm[c + 3][r] = v.w;
    }
    __syncthreads();
#pragma unroll
    for (int k = 0; k < 32; ++k) {
      float4 b  = *(const float4*)&wsm[k][tx * 4];
      float4 a0 = *(const float4*)&us[k][ty * 8];
      float4 a1 = *(const float4*)&us[k][ty * 8 + 4];
      float av[8] = {a0.x, a0.y, a0.z, a0.w, a1.x, a1.y, a1.z, a1.w};
      float bv[4] = {b.x, b.y, b.z, b.w};
#pragma unroll
      for (int i = 0; i < 8; ++i)
#pragma unroll
        for (int j = 0; j < 4; ++j) acc[i][j] = fmaf(av[i], bv[j], acc[i][j]);
    }
    __syncthreads();
  }
#pragma unroll
  for (int i = 0; i < 8; ++i) {
    float4 v = make_float4(acc[i][0], acc[i][1], acc[i][2], acc[i][3]);
    *(float4*)(Feat + (size_t)(m0 + ty * 8 + i) * FS + n0 + tx * 4) = v;
  }
}

__device__ inline float wave_sum(float v) {
#pragma unroll
  for (int off = 32; off > 0; off >>= 1) v += __shfl_xor(v, off, 64);
  return v;
}

// per-token nonlinearity, one wave per token, in-place in Feat
__global__ __launch_bounds__(64) void postA(float* __restrict__ Feat,
                                            const float* __restrict__ bias) {
  const int t = blockIdx.x, lane = threadIdx.x;
  float* f = Feat + (size_t)t * FS;
  // A -> S, C1
  float a = f[lane] + bias[lane];
  a = fminf(fmaxf(a, 0.f), 100.f);
  float S = 1.f / (1.f + 0.01f * a);
  f[lane] = S;
  f[450 + lane] = 0.1f * a * S;
  // k1
  float k10 = f[64 + lane] + bias[64 + lane];
  float k11 = f[128 + lane] + bias[128 + lane];
  float n1 = wave_sum(k10 * k10 + k11 * k11);
  float inv1 = 1.f / fmaxf(sqrtf(n1), 1e-12f);
  k10 *= inv1; k11 *= inv1;
  f[64 + lane] = k10; f[128 + lane] = k11;
  // k2
  float k20 = f[192 + lane] + bias[192 + lane];
  float k21 = f[256 + lane] + bias[256 + lane];
  float n2 = wave_sum(k20 * k20 + k21 * k21);
  float inv2 = 1.f / fmaxf(sqrtf(n2), 1e-12f);
  k20 *= inv2; k21 *= inv2;
  f[192 + lane] = k20; f[256 + lane] = k21;
  // c12
  float c12 = wave_sum(k10 * k20 + k11 * k21);
  if (lane == 0) f[514] = c12;
  // beta
  if (lane < 2) {
    float x = f[320 + lane] + bias[320 + lane];
    f[320 + lane] = 2.f / (1.f + expf(-x));
  }
  // Bt bias add
  f[322 + lane] += bias[322 + lane];
  f[386 + lane] += bias[386 + lane];
}

// chunk transition matrices: one column per thread, dots thread-local
__global__ __launch_bounds__(192) void scanB1(
    const float* __restrict__ Feat, float* __restrict__ Mc,
    float* __restrict__ dc) {
  const int cid = blockIdx.x;              // 0..255 = b*32 + chunk
  const int b = cid >> 5, ch = cid & 31;
  const int col = threadIdx.x;
  if (col > 128) return;                   // 129 active, no barriers in kernel
  float m[128];
#pragma unroll
  for (int i = 0; i < 128; ++i) m[i] = 0.f;
  const float bw = (col == 128) ? 1.f : 0.f;
  if (col < 128) m[col] = 1.f;
  const int t0 = b * TT + ch * LCH;
  for (int t = t0; t < t0 + LCH; ++t) {
    const float* __restrict__ f = Feat + (size_t)t * FS;
    // rotation R_t (per-index 2x2 on (z_i, y_i) = (m[i], m[i+64]))
#pragma unroll
    for (int i = 0; i < 64; ++i) {
      float s = f[i], c1 = f[450 + i];
      float z = m[i], y = m[i + 64];
      float sz = s * z;
      m[i]      = fmaf(-c1, y, sz);          // S z - (DT A S) y
      m[i + 64] = fmaf(s, y, 0.1f * sz);     // DT S z + S y
    }
    // both head dots on rotated state (head2 corrected via c12)
    float d1a = 0, d1b = 0, d1c = 0, d1d = 0;
    float d2a = 0, d2b = 0, d2c = 0, d2d = 0;
#pragma unroll
    for (int i = 0; i < 128; i += 4) {
      d1a = fmaf(f[64 + i + 0], m[i + 0], d1a);
      d1b = fmaf(f[64 + i + 1], m[i + 1], d1b);
      d1c = fmaf(f[64 + i + 2], m[i + 2], d1c);
      d1d = fmaf(f[64 + i + 3], m[i + 3], d1d);
      d2a = fmaf(f[192 + i + 0], m[i + 0], d2a);
      d2b = fmaf(f[192 + i + 1], m[i + 1], d2b);
      d2c = fmaf(f[192 + i + 2], m[i + 2], d2c);
      d2d = fmaf(f[192 + i + 3], m[i + 3], d2d);
    }
    float d1 = (d1a + d1b) + (d1c + d1d);
    float d2 = (d2a + d2b) + (d2c + d2d);
    float e1 = f[320] * d1;                  // beta1 * (k1 . h)
    float d2p = fmaf(-f[514], e1, d2);       // k2.h1 = k2.h - (k2.k1) e1
    float e2 = f[321] * d2p;
#pragma unroll
    for (int i = 0; i < 128; ++i) {
      float v = fmaf(-e1, f[64 + i], m[i]);
      v = fmaf(-e2, f[192 + i], v);
      m[i] = fmaf(bw, f[322 + i], v);        // d-column also gets +Bt
    }
  }
  if (col < 128) {
    float* dst = Mc + ((size_t)cid * 128 + col) * 128;
#pragma unroll
    for (int i = 0; i < 128; ++i) dst[i] = m[i];
  } else {
    float* dst = dc + (size_t)cid * 128;
#pragma unroll
    for (int i = 0; i < 128; ++i) dst[i] = m[i];
  }
}

// sequential chunk combine: h <- M_c h + d_c, store h at chunk starts
__global__ __launch_bounds__(256) void scanB2(
    const float* __restrict__ Mc, const float* __restrict__ dc,
    float* __restrict__ hstart) {
  const int b = blockIdx.x;
  const int tid = threadIdx.x;
  const int i = tid & 127, jh = tid >> 7;    // split K over 2 halves
  __shared__ float h[128];
  __shared__ float red[2][128];
  if (tid < 128) h[tid] = 0.f;
  __syncthreads();
  float mreg[64];
  {
    const float* M0 = Mc + (size_t)(b * CH) * 16384;
#pragma unroll
    for (int j = 0; j < 64; ++j) mreg[j] = M0[(size_t)(jh * 64 + j) * 128 + i];
  }
  for (int c = 0; c < CH; ++c) {
    if (tid < 128) hstart[(size_t)(b * CH + c) * 128 + tid] = h[tid];
    float acc = 0.f;
#pragma unroll
    for (int j = 0; j < 64; ++j) acc = fmaf(mreg[j], h[jh * 64 + j], acc);
    red[jh][i] = acc;
    if (c + 1 < CH) {                        // prefetch next chunk's matrix
      const float* Mn = Mc + (size_t)(b * CH + c + 1) * 16384;
#pragma unroll
      for (int j = 0; j < 64; ++j) mreg[j] = Mn[(size_t)(jh * 64 + j) * 128 + i];
    }
    __syncthreads();
    if (tid < 128)
      h[tid] = red[0][tid] + red[1][tid] + dc[(size_t)(b * CH + c) * 128 + tid];
    __syncthreads();
  }
}

// replay within chunk from h_start, one wave per chunk, write hs
__global__ __launch_bounds__(64) void scanB3(
    const float* __restrict__ Feat, const float* __restrict__ hstart,
    float* __restrict__ hs) {
  const int cid = blockIdx.x;
  const int b = cid >> 5, ch = cid & 31;
  const int lane = threadIdx.x;
  float z = hstart[(size_t)cid * 128 + lane];
  float y = hstart[(size_t)cid * 128 + 64 + lane];
  const int t0 = b * TT + ch * LCH;
  for (int t = t0; t < t0 + LCH; ++t) {
    const float* __restrict__ f = Feat + (size_t)t * FS;
    float s = f[lane], c1 = f[450 + lane];
    float k1z = f[64 + lane], k1y = f[128 + lane];
    float k2z = f[192 + lane], k2y = f[256 + lane];
    float bz = f[322 + lane], by = f[386 + lane];
    float b1 = f[320], b2 = f[321], c12 = f[514];
    float sz = s * z;
    float zn = fmaf(-c1, y, sz);
    float yn = fmaf(s, y, 0.1f * sz);
    float p = fmaf(k1y, yn, k1z * zn);
    float q = fmaf(k2y, yn, k2z * zn);
#pragma unroll
    for (int off = 32; off > 0; off >>= 1) {
      p += __shfl_xor(p, off, 64);
      q += __shfl_xor(q, off, 64);
    }
    float e1 = b1 * p;
    float d2 = fmaf(-c12, e1, q);
    float e2 = b2 * d2;
    zn = fmaf(-e1, k1z, zn); zn = fmaf(-e2, k2z, zn); zn += bz;
    yn = fmaf(-e1, k1y, yn); yn = fmaf(-e2, k2y, yn); yn += by;
    hs[(size_t)t * 128 + lane] = zn;
    hs[(size_t)t * 128 + 64 + lane] = yn;
    z = zn; y = yn;
  }
}

// out = hs @ C^T + u*D : tile 64 tokens x 64 dims, K=128 in 2 halves
__global__ __launch_bounds__(256) void gemmC(
    const float* __restrict__ hs, const float* __restrict__ Cm,
    const float* __restrict__ u, const float* __restrict__ Dv,
    float* __restrict__ out) {
  __shared__ float as[64][68];   // [k][token]
  __shared__ float bs[64][68];   // [k][dim]
  const int tid = threadIdx.x;
  const int tx = tid & 15, ty = tid >> 4;
  const int t0 = blockIdx.x * 64;
  const int d0 = blockIdx.y * 64;
  float acc[4][4];
#pragma unroll
  for (int i = 0; i < 4; ++i)
#pragma unroll
    for (int j = 0; j < 4; ++j) acc[i][j] = 0.f;

  for (int k0 = 0; k0 < 128; k0 += 64) {
#pragma unroll
    for (int l = 0; l < 4; ++l) {
      int idx = tid + l * 256;           // 0..1023 over 64r x 16 float4
      int r = idx >> 4, c = (idx & 15) * 4;
      float4 v = *(const float4*)(hs + (size_t)(t0 + r) * 128 + k0 + c);
      as[c + 0][r] = v.x; as[c + 1][r] = v.y; as[c + 2][r] = v.z; as[c + 3][r] = v.w;
      float4 w = *(const float4*)(Cm + (size_t)(d0 + r) * 128 + k0 + c);
      bs[c + 0][r] = w.x; bs[c + 1][r] = w.y; bs[c + 2][r] = w.z; bs[c + 3][r] = w.w;
    }
    __syncthreads();
#pragma unroll
    for (int k = 0; k < 64; ++k) {
      float4 a = *(const float4*)&as[k][ty * 4];
      float4 b = *(const float4*)&bs[k][tx * 4];
      float av[4] = {a.x, a.y, a.z, a.w};
      float bv[4] = {b.x, b.y, b.z, b.w};
#pragma unroll
      for (int i = 0; i < 4; ++i)
#pragma unroll
        for (int j = 0; j < 4; ++j) acc[i][j] = fmaf(av[i], bv[j], acc[i][j]);
    }
    __syncthreads();
  }
#pragma unroll
  for (int i = 0; i < 4; ++i) {
    int row = t0 + ty * 4 + i;
    float4 uv = *(const float4*)(u + (size_t)row * DM + d0 + tx * 4);
    float4 dv = *(const float4*)(Dv + d0 + tx * 4);
    float4 o;
    o.x = fmaf(uv.x, dv.x, acc[i][0]);
    o.y = fmaf(uv.y, dv.y, acc[i][1]);
    o.z = fmaf(uv.z, dv.z, acc[i][2]);
    o.w = fmaf(uv.w, dv.w, acc[i][3]);
    *(float4*)(out + (size_t)row * DM + d0 + tx * 4) = o;
  }
}

extern "C" void kernel_launch(void* const* d_in, const int* in_sizes, int n_in,
                              void* d_out, int out_size, void* d_ws, size_t ws_size,
                              hipStream_t stream) {
  const float* u      = (const float*)d_in[0];
  const float* W_A    = (const float*)d_in[1];
  const float* b_A    = (const float*)d_in[2];
  const float* W_k    = (const float*)d_in[3];
  const float* b_k    = (const float*)d_in[4];
  const float* W_beta = (const float*)d_in[5];
  const float* b_beta = (const float*)d_in[6];
  const float* B_w    = (const float*)d_in[7];
  const float* B_b    = (const float*)d_in[8];
  const float* Cm     = (const float*)d_in[9];
  const float* Dv     = (const float*)d_in[10];
  float* out = (float*)d_out;
  char* ws = (char*)d_ws;
  // workspace carve-up (61.6 MB total)
  float* Wp     = (float*)(ws);                 // 512*1024*4       = 2,097,152
  float* bias   = (float*)(ws + 2097152);       // 512*4 (pad 4096)
  float* Feat   = (float*)(ws + 2101248);       // 16384*520*4      = 34,078,720
  float* Mc     = (float*)(ws + 36179968);      // 256*128*128*4    = 16,777,216
  float* dcv    = (float*)(ws + 52957184);      // 256*128*4        = 131,072
  float* hstart = (float*)(ws + 53088256);      // 256*128*4        = 131,072
  float* hsb    = (float*)(ws + 53219328);      // 16384*128*4      = 8,388,608

  packW<<<dim3(512), dim3(256), 0, stream>>>(W_A, b_A, W_k, b_k, W_beta, b_beta,
                                             B_w, B_b, Wp, bias);
  gemmA<<<dim3(128, 8), dim3(256), 0, stream>>>(u, Wp, Feat);
  postA<<<dim3(16384), dim3(64), 0, stream>>>(Feat, bias);
  scanB1<<<dim3(256), dim3(192), 0, stream>>>(Feat, Mc, dcv);
  scanB2<<<dim3(8), dim3(256), 0, stream>>>(Mc, dcv, hstart);
  scanB3<<<dim3(256), dim3(64), 0, stream>>>(Feat, hstart, hsb);
  gemmC<<<dim3(256, 16), dim3(256), 0, stream>>>(hsb, Cm, u, Dv, out);
}

// Round 2
// 1536.203 us; speedup vs baseline: 1.0609x; 1.0609x over previous
//
#include <hip/hip_runtime.h>
#include <cmath>

// ---------------------------------------------------------------------------
// OHDeltaProductSSM: u(8,2048,1024) -> out(8,2048,1024), fp32.
// Pipeline:
//   packW  : gather all weight rows into Wp[512][1024] (+bias[512])
//   gemmA  : Feat_raw[t][0..512) = u[t] . Wp[n]   (fp32 tiled GEMM)
//   postA  : per-token nonlinearity: S, C1=DT*A*S, normalized k1/k2, beta,
//            Bt, c12=k1.k2   (in-place in Feat, stride FS=520)
//   scanB1 : per (batch,chunk of 64 steps): evolve the 128 unit columns ->
//            chunk transition M_c (128x128). One column per thread, 128
//            threads/block, __launch_bounds__(128,1) so m[128] stays in VGPRs.
//   scanB0 : affine replay from h=0 per chunk (1 wave, shuffle dots) -> d_c.
//   scanB2 : sequential combine over 32 chunks/batch: h <- M_c h + d_c,
//            records h at each chunk start.
//   scanB3 : replay each chunk (1 wave, 64 steps) from its h_start, writing
//            all per-token states hs[t][128].
//   gemmC  : out[t][d] = hs[t] . C[d] + u[t][d]*D[d]
// Feat layout per token (FS=520 floats):
//   [0,64)=S  [64,192)=k1  [192,320)=k2  [320]=b1 [321]=b2
//   [322,450)=Bt  [450,514)=C1  [514]=c12
// ---------------------------------------------------------------------------

#define NTOK 16384
#define TT 2048
#define BB 8
#define DM 1024
#define FS 520
#define CH 32
#define LCH 64

__global__ __launch_bounds__(256) void packW(
    const float* __restrict__ W_A, const float* __restrict__ b_A,
    const float* __restrict__ W_k, const float* __restrict__ b_k,
    const float* __restrict__ W_beta, const float* __restrict__ b_beta,
    const float* __restrict__ B_w, const float* __restrict__ B_b,
    float* __restrict__ Wp, float* __restrict__ bias) {
  int r = blockIdx.x;          // 0..511
  int tid = threadIdx.x;       // 256 threads, one float4 each (1024 floats/row)
  const float* src = nullptr;
  float bv = 0.f;
  if (r < 64)       { src = W_A    + (size_t)r * DM;       bv = b_A[r]; }
  else if (r < 320) { src = W_k    + (size_t)(r - 64) * DM; bv = b_k[r - 64]; }
  else if (r < 322) { src = W_beta + (size_t)(r - 320) * DM; bv = b_beta[r - 320]; }
  else if (r < 450) { src = B_w    + (size_t)(r - 322) * DM; bv = B_b[r - 322]; }
  float4* dst = (float4*)(Wp + (size_t)r * DM);
  if (src) dst[tid] = ((const float4*)src)[tid];
  else     dst[tid] = make_float4(0.f, 0.f, 0.f, 0.f);
  if (tid == 0) bias[r] = bv;
}

// Feat_raw = u @ Wp^T : tile 128 tokens x 64 feats, BK=32
__global__ __launch_bounds__(256) void gemmA(
    const float* __restrict__ u, const float* __restrict__ Wp,
    float* __restrict__ Feat) {
  __shared__ float us[32][132];   // [k][m], stride 132 floats (528B, 16B mult)
  __shared__ float wsm[32][68];   // [k][n]
  const int tid = threadIdx.x;
  const int tx = tid & 15, ty = tid >> 4;
  const int m0 = blockIdx.x * 128;
  const int n0 = blockIdx.y * 64;
  float acc[8][4];
#pragma unroll
  for (int i = 0; i < 8; ++i)
#pragma unroll
    for (int j = 0; j < 4; ++j) acc[i][j] = 0.f;

  for (int k0 = 0; k0 < DM; k0 += 32) {
#pragma unroll
    for (int l = 0; l < 4; ++l) {        // u tile: 128x32
      int idx = tid + l * 256;
      int r = idx >> 3, c = (idx & 7) * 4;
      float4 v = *(const float4*)(u + (size_t)(m0 + r) * DM + k0 + c);
      us[c + 0][r] = v.x; us[c + 1][r] = v.y; us[c + 2][r] = v.z; us[c + 3][r] = v.w;
    }
#pragma unroll
    for (int l = 0; l < 2; ++l) {        // W tile: 64x32
      int idx = tid + l * 256;
      int r = idx >> 3, c = (idx & 7) * 4;
      float4 v = *(const float4*)(Wp + (size_t)(n0 + r) * DM + k0 + c);
      wsm[c + 0][r] = v.x; wsm[c + 1][r] = v.y; wsm[c + 2][r] = v.z; wsm[c + 3][r] = v.w;
    }
    __syncthreads();
#pragma unroll
    for (int k = 0; k < 32; ++k) {
      float4 b  = *(const float4*)&wsm[k][tx * 4];
      float4 a0 = *(const float4*)&us[k][ty * 8];
      float4 a1 = *(const float4*)&us[k][ty * 8 + 4];
      float av[8] = {a0.x, a0.y, a0.z, a0.w, a1.x, a1.y, a1.z, a1.w};
      float bv[4] = {b.x, b.y, b.z, b.w};
#pragma unroll
      for (int i = 0; i < 8; ++i)
#pragma unroll
        for (int j = 0; j < 4; ++j) acc[i][j] = fmaf(av[i], bv[j], acc[i][j]);
    }
    __syncthreads();
  }
#pragma unroll
  for (int i = 0; i < 8; ++i) {
    float4 v = make_float4(acc[i][0], acc[i][1], acc[i][2], acc[i][3]);
    *(float4*)(Feat + (size_t)(m0 + ty * 8 + i) * FS + n0 + tx * 4) = v;
  }
}

__device__ inline float wave_sum(float v) {
#pragma unroll
  for (int off = 32; off > 0; off >>= 1) v += __shfl_xor(v, off, 64);
  return v;
}

// per-token nonlinearity, one wave per token, in-place in Feat
__global__ __launch_bounds__(64) void postA(float* __restrict__ Feat,
                                            const float* __restrict__ bias) {
  const int t = blockIdx.x, lane = threadIdx.x;
  float* f = Feat + (size_t)t * FS;
  // A -> S, C1
  float a = f[lane] + bias[lane];
  a = fminf(fmaxf(a, 0.f), 100.f);
  float S = 1.f / (1.f + 0.01f * a);
  f[lane] = S;
  f[450 + lane] = 0.1f * a * S;
  // k1
  float k10 = f[64 + lane] + bias[64 + lane];
  float k11 = f[128 + lane] + bias[128 + lane];
  float n1 = wave_sum(k10 * k10 + k11 * k11);
  float inv1 = 1.f / fmaxf(sqrtf(n1), 1e-12f);
  k10 *= inv1; k11 *= inv1;
  f[64 + lane] = k10; f[128 + lane] = k11;
  // k2
  float k20 = f[192 + lane] + bias[192 + lane];
  float k21 = f[256 + lane] + bias[256 + lane];
  float n2 = wave_sum(k20 * k20 + k21 * k21);
  float inv2 = 1.f / fmaxf(sqrtf(n2), 1e-12f);
  k20 *= inv2; k21 *= inv2;
  f[192 + lane] = k20; f[256 + lane] = k21;
  // c12
  float c12 = wave_sum(k10 * k20 + k11 * k21);
  if (lane == 0) f[514] = c12;
  // beta
  if (lane < 2) {
    float x = f[320 + lane] + bias[320 + lane];
    f[320 + lane] = 2.f / (1.f + expf(-x));
  }
  // Bt bias add
  f[322 + lane] += bias[322 + lane];
  f[386 + lane] += bias[386 + lane];
}

// chunk transition matrices: one column per thread, dots thread-local.
// 128 threads/block, min-1-wave launch bounds => m[128] stays in registers.
__global__ __launch_bounds__(128, 1) void scanB1(
    const float* __restrict__ Feat, float* __restrict__ Mc) {
  const int cid = blockIdx.x;              // 0..255 = b*32 + chunk
  const int b = cid >> 5, ch = cid & 31;
  const int col = threadIdx.x;             // 0..127
  float m[128];
#pragma unroll
  for (int i = 0; i < 128; ++i) m[i] = 0.f;
  m[col] = 1.f;
  const int t0 = b * TT + ch * LCH;
  for (int t = t0; t < t0 + LCH; ++t) {
    const float* __restrict__ f = Feat + (size_t)t * FS;
    // rotation R_t (per-index 2x2 on (z_i, y_i) = (m[i], m[i+64]))
#pragma unroll
    for (int i = 0; i < 64; ++i) {
      float s = f[i], c1 = f[450 + i];
      float z = m[i], y = m[i + 64];
      float sz = s * z;
      m[i]      = fmaf(-c1, y, sz);          // S z - (DT A S) y
      m[i + 64] = fmaf(s, y, 0.1f * sz);     // DT S z + S y
    }
    // both head dots on rotated state (head2 corrected via c12)
    float d1a = 0, d1b = 0, d1c = 0, d1d = 0;
    float d2a = 0, d2b = 0, d2c = 0, d2d = 0;
#pragma unroll
    for (int i = 0; i < 128; i += 4) {
      d1a = fmaf(f[64 + i + 0], m[i + 0], d1a);
      d1b = fmaf(f[64 + i + 1], m[i + 1], d1b);
      d1c = fmaf(f[64 + i + 2], m[i + 2], d1c);
      d1d = fmaf(f[64 + i + 3], m[i + 3], d1d);
      d2a = fmaf(f[192 + i + 0], m[i + 0], d2a);
      d2b = fmaf(f[192 + i + 1], m[i + 1], d2b);
      d2c = fmaf(f[192 + i + 2], m[i + 2], d2c);
      d2d = fmaf(f[192 + i + 3], m[i + 3], d2d);
    }
    float d1 = (d1a + d1b) + (d1c + d1d);
    float d2 = (d2a + d2b) + (d2c + d2d);
    float e1 = f[320] * d1;                  // beta1 * (k1 . h)
    float d2p = fmaf(-f[514], e1, d2);       // k2.h1 = k2.h - (k2.k1) e1
    float e2 = f[321] * d2p;
#pragma unroll
    for (int i = 0; i < 128; ++i) {
      float v = fmaf(-e1, f[64 + i], m[i]);
      m[i] = fmaf(-e2, f[192 + i], v);
    }
  }
  float* dst = Mc + ((size_t)cid * 128 + col) * 128;
#pragma unroll
  for (int i = 0; i < 128; ++i) dst[i] = m[i];
}

// offset column d_c: affine replay from h=0, one wave per chunk
__global__ __launch_bounds__(64) void scanB0(
    const float* __restrict__ Feat, float* __restrict__ dc) {
  const int cid = blockIdx.x;
  const int b = cid >> 5, ch = cid & 31;
  const int lane = threadIdx.x;
  float z = 0.f, y = 0.f;
  const int t0 = b * TT + ch * LCH;
  for (int t = t0; t < t0 + LCH; ++t) {
    const float* __restrict__ f = Feat + (size_t)t * FS;
    float s = f[lane], c1 = f[450 + lane];
    float k1z = f[64 + lane], k1y = f[128 + lane];
    float k2z = f[192 + lane], k2y = f[256 + lane];
    float bz = f[322 + lane], by = f[386 + lane];
    float b1 = f[320], b2 = f[321], c12 = f[514];
    float sz = s * z;
    float zn = fmaf(-c1, y, sz);
    float yn = fmaf(s, y, 0.1f * sz);
    float p = fmaf(k1y, yn, k1z * zn);
    float q = fmaf(k2y, yn, k2z * zn);
#pragma unroll
    for (int off = 32; off > 0; off >>= 1) {
      p += __shfl_xor(p, off, 64);
      q += __shfl_xor(q, off, 64);
    }
    float e1 = b1 * p;
    float d2 = fmaf(-c12, e1, q);
    float e2 = b2 * d2;
    z = fmaf(-e1, k1z, zn); z = fmaf(-e2, k2z, z); z += bz;
    y = fmaf(-e1, k1y, yn); y = fmaf(-e2, k2y, y); y += by;
  }
  dc[(size_t)cid * 128 + lane] = z;
  dc[(size_t)cid * 128 + 64 + lane] = y;
}

// sequential chunk combine: h <- M_c h + d_c, store h at chunk starts
__global__ __launch_bounds__(256) void scanB2(
    const float* __restrict__ Mc, const float* __restrict__ dc,
    float* __restrict__ hstart) {
  const int b = blockIdx.x;
  const int tid = threadIdx.x;
  const int i = tid & 127, jh = tid >> 7;    // split K over 2 halves
  __shared__ float h[128];
  __shared__ float red[2][128];
  if (tid < 128) h[tid] = 0.f;
  __syncthreads();
  float mreg[64];
  {
    const float* M0 = Mc + (size_t)(b * CH) * 16384;
#pragma unroll
    for (int j = 0; j < 64; ++j) mreg[j] = M0[(size_t)(jh * 64 + j) * 128 + i];
  }
  for (int c = 0; c < CH; ++c) {
    if (tid < 128) hstart[(size_t)(b * CH + c) * 128 + tid] = h[tid];
    float acc = 0.f;
#pragma unroll
    for (int j = 0; j < 64; ++j) acc = fmaf(mreg[j], h[jh * 64 + j], acc);
    red[jh][i] = acc;
    if (c + 1 < CH) {                        // prefetch next chunk's matrix
      const float* Mn = Mc + (size_t)(b * CH + c + 1) * 16384;
#pragma unroll
      for (int j = 0; j < 64; ++j) mreg[j] = Mn[(size_t)(jh * 64 + j) * 128 + i];
    }
    __syncthreads();
    if (tid < 128)
      h[tid] = red[0][tid] + red[1][tid] + dc[(size_t)(b * CH + c) * 128 + tid];
    __syncthreads();
  }
}

// replay within chunk from h_start, one wave per chunk, write hs
__global__ __launch_bounds__(64) void scanB3(
    const float* __restrict__ Feat, const float* __restrict__ hstart,
    float* __restrict__ hs) {
  const int cid = blockIdx.x;
  const int b = cid >> 5, ch = cid & 31;
  const int lane = threadIdx.x;
  float z = hstart[(size_t)cid * 128 + lane];
  float y = hstart[(size_t)cid * 128 + 64 + lane];
  const int t0 = b * TT + ch * LCH;
  for (int t = t0; t < t0 + LCH; ++t) {
    const float* __restrict__ f = Feat + (size_t)t * FS;
    float s = f[lane], c1 = f[450 + lane];
    float k1z = f[64 + lane], k1y = f[128 + lane];
    float k2z = f[192 + lane], k2y = f[256 + lane];
    float bz = f[322 + lane], by = f[386 + lane];
    float b1 = f[320], b2 = f[321], c12 = f[514];
    float sz = s * z;
    float zn = fmaf(-c1, y, sz);
    float yn = fmaf(s, y, 0.1f * sz);
    float p = fmaf(k1y, yn, k1z * zn);
    float q = fmaf(k2y, yn, k2z * zn);
#pragma unroll
    for (int off = 32; off > 0; off >>= 1) {
      p += __shfl_xor(p, off, 64);
      q += __shfl_xor(q, off, 64);
    }
    float e1 = b1 * p;
    float d2 = fmaf(-c12, e1, q);
    float e2 = b2 * d2;
    zn = fmaf(-e1, k1z, zn); zn = fmaf(-e2, k2z, zn); zn += bz;
    yn = fmaf(-e1, k1y, yn); yn = fmaf(-e2, k2y, yn); yn += by;
    hs[(size_t)t * 128 + lane] = zn;
    hs[(size_t)t * 128 + 64 + lane] = yn;
    z = zn; y = yn;
  }
}

// out = hs @ C^T + u*D : tile 64 tokens x 64 dims, K=128 in 2 halves
__global__ __launch_bounds__(256) void gemmC(
    const float* __restrict__ hs, const float* __restrict__ Cm,
    const float* __restrict__ u, const float* __restrict__ Dv,
    float* __restrict__ out) {
  __shared__ float as[64][68];   // [k][token]
  __shared__ float bs[64][68];   // [k][dim]
  const int tid = threadIdx.x;
  const int tx = tid & 15, ty = tid >> 4;
  const int t0 = blockIdx.x * 64;
  const int d0 = blockIdx.y * 64;
  float acc[4][4];
#pragma unroll
  for (int i = 0; i < 4; ++i)
#pragma unroll
    for (int j = 0; j < 4; ++j) acc[i][j] = 0.f;

  for (int k0 = 0; k0 < 128; k0 += 64) {
#pragma unroll
    for (int l = 0; l < 4; ++l) {
      int idx = tid + l * 256;           // 0..1023 over 64r x 16 float4
      int r = idx >> 4, c = (idx & 15) * 4;
      float4 v = *(const float4*)(hs + (size_t)(t0 + r) * 128 + k0 + c);
      as[c + 0][r] = v.x; as[c + 1][r] = v.y; as[c + 2][r] = v.z; as[c + 3][r] = v.w;
      float4 w = *(const float4*)(Cm + (size_t)(d0 + r) * 128 + k0 + c);
      bs[c + 0][r] = w.x; bs[c + 1][r] = w.y; bs[c + 2][r] = w.z; bs[c + 3][r] = w.w;
    }
    __syncthreads();
#pragma unroll
    for (int k = 0; k < 64; ++k) {
      float4 a = *(const float4*)&as[k][ty * 4];
      float4 b = *(const float4*)&bs[k][tx * 4];
      float av[4] = {a.x, a.y, a.z, a.w};
      float bv[4] = {b.x, b.y, b.z, b.w};
#pragma unroll
      for (int i = 0; i < 4; ++i)
#pragma unroll
        for (int j = 0; j < 4; ++j) acc[i][j] = fmaf(av[i], bv[j], acc[i][j]);
    }
    __syncthreads();
  }
#pragma unroll
  for (int i = 0; i < 4; ++i) {
    int row = t0 + ty * 4 + i;
    float4 uv = *(const float4*)(u + (size_t)row * DM + d0 + tx * 4);
    float4 dv = *(const float4*)(Dv + d0 + tx * 4);
    float4 o;
    o.x = fmaf(uv.x, dv.x, acc[i][0]);
    o.y = fmaf(uv.y, dv.y, acc[i][1]);
    o.z = fmaf(uv.z, dv.z, acc[i][2]);
    o.w = fmaf(uv.w, dv.w, acc[i][3]);
    *(float4*)(out + (size_t)row * DM + d0 + tx * 4) = o;
  }
}

extern "C" void kernel_launch(void* const* d_in, const int* in_sizes, int n_in,
                              void* d_out, int out_size, void* d_ws, size_t ws_size,
                              hipStream_t stream) {
  const float* u      = (const float*)d_in[0];
  const float* W_A    = (const float*)d_in[1];
  const float* b_A    = (const float*)d_in[2];
  const float* W_k    = (const float*)d_in[3];
  const float* b_k    = (const float*)d_in[4];
  const float* W_beta = (const float*)d_in[5];
  const float* b_beta = (const float*)d_in[6];
  const float* B_w    = (const float*)d_in[7];
  const float* B_b    = (const float*)d_in[8];
  const float* Cm     = (const float*)d_in[9];
  const float* Dv     = (const float*)d_in[10];
  float* out = (float*)d_out;
  char* ws = (char*)d_ws;
  // workspace carve-up (61.6 MB total)
  float* Wp     = (float*)(ws);                 // 512*1024*4       = 2,097,152
  float* bias   = (float*)(ws + 2097152);       // 512*4 (pad 4096)
  float* Feat   = (float*)(ws + 2101248);       // 16384*520*4      = 34,078,720
  float* Mc     = (float*)(ws + 36179968);      // 256*128*128*4    = 16,777,216
  float* dcv    = (float*)(ws + 52957184);      // 256*128*4        = 131,072
  float* hstart = (float*)(ws + 53088256);      // 256*128*4        = 131,072
  float* hsb    = (float*)(ws + 53219328);      // 16384*128*4      = 8,388,608

  packW<<<dim3(512), dim3(256), 0, stream>>>(W_A, b_A, W_k, b_k, W_beta, b_beta,
                                             B_w, B_b, Wp, bias);
  gemmA<<<dim3(128, 8), dim3(256), 0, stream>>>(u, Wp, Feat);
  postA<<<dim3(16384), dim3(64), 0, stream>>>(Feat, bias);
  scanB1<<<dim3(256), dim3(128), 0, stream>>>(Feat, Mc);
  scanB0<<<dim3(256), dim3(64), 0, stream>>>(Feat, dcv);
  scanB2<<<dim3(8), dim3(256), 0, stream>>>(Mc, dcv, hstart);
  scanB3<<<dim3(256), dim3(64), 0, stream>>>(Feat, hstart, hsb);
  gemmC<<<dim3(256, 16), dim3(256), 0, stream>>>(hsb, Cm, u, Dv, out);
}

// Round 3
// 942.327 us; speedup vs baseline: 1.7295x; 1.6302x over previous
//
#include <hip/hip_runtime.h>
#include <cmath>

// ---------------------------------------------------------------------------
// OHDeltaProductSSM: u(8,2048,1024) -> out(8,2048,1024), fp32.
// Pipeline:
//   packW  : gather all weight rows into Wp[512][1024] (+bias[512])
//   gemmA  : Feat_raw[t][0..512) = u[t] . Wp[n]   (fp32 tiled GEMM)
//   postA  : per-token nonlinearity: S, C1=DT*A*S, normalized k1/k2, beta,
//            Bt, c12=k1.k2   (in-place in Feat, stride FS=520)
//   scanB1 : per (batch,chunk of 64 steps): evolve the 128 unit columns ->
//            chunk transition M_c (128x128). One column per thread.
//            NOTE: no dynamic indexing into m[] anywhere — a single
//            m[threadIdx.x]=1 store demotes the whole array to scratch
//            (round-1/2 bug: VGPR=48, 350MB spill writes).
//   scanB0 : affine replay from h=0 per chunk (1 wave, shuffle dots) -> d_c.
//   scanB2 : sequential combine over 32 chunks/batch: h <- M_c h + d_c,
//            records h at each chunk start.
//   scanB3 : replay each chunk (1 wave, 64 steps) from its h_start, writing
//            all per-token states hs[t][128].
//   gemmC  : out[t][d] = hs[t] . C[d] + u[t][d]*D[d]
// Feat layout per token (FS=520 floats):
//   [0,64)=S  [64,192)=k1  [192,320)=k2  [320]=b1 [321]=b2
//   [322,450)=Bt  [450,514)=C1  [514]=c12
// ---------------------------------------------------------------------------

#define NTOK 16384
#define TT 2048
#define BB 8
#define DM 1024
#define FS 520
#define CH 32
#define LCH 64

__global__ __launch_bounds__(256) void packW(
    const float* __restrict__ W_A, const float* __restrict__ b_A,
    const float* __restrict__ W_k, const float* __restrict__ b_k,
    const float* __restrict__ W_beta, const float* __restrict__ b_beta,
    const float* __restrict__ B_w, const float* __restrict__ B_b,
    float* __restrict__ Wp, float* __restrict__ bias) {
  int r = blockIdx.x;          // 0..511
  int tid = threadIdx.x;       // 256 threads, one float4 each (1024 floats/row)
  const float* src = nullptr;
  float bv = 0.f;
  if (r < 64)       { src = W_A    + (size_t)r * DM;       bv = b_A[r]; }
  else if (r < 320) { src = W_k    + (size_t)(r - 64) * DM; bv = b_k[r - 64]; }
  else if (r < 322) { src = W_beta + (size_t)(r - 320) * DM; bv = b_beta[r - 320]; }
  else if (r < 450) { src = B_w    + (size_t)(r - 322) * DM; bv = B_b[r - 322]; }
  float4* dst = (float4*)(Wp + (size_t)r * DM);
  if (src) dst[tid] = ((const float4*)src)[tid];
  else     dst[tid] = make_float4(0.f, 0.f, 0.f, 0.f);
  if (tid == 0) bias[r] = bv;
}

// Feat_raw = u @ Wp^T : tile 128 tokens x 64 feats, BK=32
__global__ __launch_bounds__(256) void gemmA(
    const float* __restrict__ u, const float* __restrict__ Wp,
    float* __restrict__ Feat) {
  __shared__ float us[32][132];   // [k][m], stride 132 floats (528B, 16B mult)
  __shared__ float wsm[32][68];   // [k][n]
  const int tid = threadIdx.x;
  const int tx = tid & 15, ty = tid >> 4;
  const int m0 = blockIdx.x * 128;
  const int n0 = blockIdx.y * 64;
  float acc[8][4];
#pragma unroll
  for (int i = 0; i < 8; ++i)
#pragma unroll
    for (int j = 0; j < 4; ++j) acc[i][j] = 0.f;

  for (int k0 = 0; k0 < DM; k0 += 32) {
#pragma unroll
    for (int l = 0; l < 4; ++l) {        // u tile: 128x32
      int idx = tid + l * 256;
      int r = idx >> 3, c = (idx & 7) * 4;
      float4 v = *(const float4*)(u + (size_t)(m0 + r) * DM + k0 + c);
      us[c + 0][r] = v.x; us[c + 1][r] = v.y; us[c + 2][r] = v.z; us[c + 3][r] = v.w;
    }
#pragma unroll
    for (int l = 0; l < 2; ++l) {        // W tile: 64x32
      int idx = tid + l * 256;
      int r = idx >> 3, c = (idx & 7) * 4;
      float4 v = *(const float4*)(Wp + (size_t)(n0 + r) * DM + k0 + c);
      wsm[c + 0][r] = v.x; wsm[c + 1][r] = v.y; wsm[c + 2][r] = v.z; wsm[c + 3][r] = v.w;
    }
    __syncthreads();
#pragma unroll
    for (int k = 0; k < 32; ++k) {
      float4 b  = *(const float4*)&wsm[k][tx * 4];
      float4 a0 = *(const float4*)&us[k][ty * 8];
      float4 a1 = *(const float4*)&us[k][ty * 8 + 4];
      float av[8] = {a0.x, a0.y, a0.z, a0.w, a1.x, a1.y, a1.z, a1.w};
      float bv[4] = {b.x, b.y, b.z, b.w};
#pragma unroll
      for (int i = 0; i < 8; ++i)
#pragma unroll
        for (int j = 0; j < 4; ++j) acc[i][j] = fmaf(av[i], bv[j], acc[i][j]);
    }
    __syncthreads();
  }
#pragma unroll
  for (int i = 0; i < 8; ++i) {
    float4 v = make_float4(acc[i][0], acc[i][1], acc[i][2], acc[i][3]);
    *(float4*)(Feat + (size_t)(m0 + ty * 8 + i) * FS + n0 + tx * 4) = v;
  }
}

__device__ inline float wave_sum(float v) {
#pragma unroll
  for (int off = 32; off > 0; off >>= 1) v += __shfl_xor(v, off, 64);
  return v;
}

// per-token nonlinearity, one wave per token, in-place in Feat
__global__ __launch_bounds__(64) void postA(float* __restrict__ Feat,
                                            const float* __restrict__ bias) {
  const int t = blockIdx.x, lane = threadIdx.x;
  float* f = Feat + (size_t)t * FS;
  // A -> S, C1
  float a = f[lane] + bias[lane];
  a = fminf(fmaxf(a, 0.f), 100.f);
  float S = 1.f / (1.f + 0.01f * a);
  f[lane] = S;
  f[450 + lane] = 0.1f * a * S;
  // k1
  float k10 = f[64 + lane] + bias[64 + lane];
  float k11 = f[128 + lane] + bias[128 + lane];
  float n1 = wave_sum(k10 * k10 + k11 * k11);
  float inv1 = 1.f / fmaxf(sqrtf(n1), 1e-12f);
  k10 *= inv1; k11 *= inv1;
  f[64 + lane] = k10; f[128 + lane] = k11;
  // k2
  float k20 = f[192 + lane] + bias[192 + lane];
  float k21 = f[256 + lane] + bias[256 + lane];
  float n2 = wave_sum(k20 * k20 + k21 * k21);
  float inv2 = 1.f / fmaxf(sqrtf(n2), 1e-12f);
  k20 *= inv2; k21 *= inv2;
  f[192 + lane] = k20; f[256 + lane] = k21;
  // c12
  float c12 = wave_sum(k10 * k20 + k11 * k21);
  if (lane == 0) f[514] = c12;
  // beta
  if (lane < 2) {
    float x = f[320 + lane] + bias[320 + lane];
    f[320 + lane] = 2.f / (1.f + expf(-x));
  }
  // Bt bias add
  f[322 + lane] += bias[322 + lane];
  f[386 + lane] += bias[386 + lane];
}

// chunk transition matrices: one column per thread, dots thread-local.
// All m[] accesses use compile-time-constant indices (full unroll) so the
// array lives in VGPRs; launch_bounds(128,1) lifts the register cap.
__global__ __launch_bounds__(128, 1) void scanB1(
    const float* __restrict__ Feat, float* __restrict__ Mc) {
  const int cid = blockIdx.x;              // 0..255 = b*32 + chunk
  const int b = cid >> 5, ch = cid & 31;
  const int col = threadIdx.x;             // 0..127
  float m[128];
#pragma unroll
  for (int i = 0; i < 128; ++i) m[i] = (i == col) ? 1.f : 0.f;
  const int t0 = b * TT + ch * LCH;
  for (int t = t0; t < t0 + LCH; ++t) {
    const float* __restrict__ f = Feat + (size_t)t * FS;
    // rotation R_t (per-index 2x2 on (z_i, y_i) = (m[i], m[i+64]))
#pragma unroll
    for (int i = 0; i < 64; ++i) {
      float s = f[i], c1 = f[450 + i];
      float z = m[i], y = m[i + 64];
      float sz = s * z;
      m[i]      = fmaf(-c1, y, sz);          // S z - (DT A S) y
      m[i + 64] = fmaf(s, y, 0.1f * sz);     // DT S z + S y
    }
    // both head dots on rotated state (head2 corrected via c12)
    float d1a = 0, d1b = 0, d1c = 0, d1d = 0;
    float d2a = 0, d2b = 0, d2c = 0, d2d = 0;
#pragma unroll
    for (int i = 0; i < 128; i += 4) {
      d1a = fmaf(f[64 + i + 0], m[i + 0], d1a);
      d1b = fmaf(f[64 + i + 1], m[i + 1], d1b);
      d1c = fmaf(f[64 + i + 2], m[i + 2], d1c);
      d1d = fmaf(f[64 + i + 3], m[i + 3], d1d);
      d2a = fmaf(f[192 + i + 0], m[i + 0], d2a);
      d2b = fmaf(f[192 + i + 1], m[i + 1], d2b);
      d2c = fmaf(f[192 + i + 2], m[i + 2], d2c);
      d2d = fmaf(f[192 + i + 3], m[i + 3], d2d);
    }
    float d1 = (d1a + d1b) + (d1c + d1d);
    float d2 = (d2a + d2b) + (d2c + d2d);
    float e1 = f[320] * d1;                  // beta1 * (k1 . h)
    float d2p = fmaf(-f[514], e1, d2);       // k2.h1 = k2.h - (k2.k1) e1
    float e2 = f[321] * d2p;
#pragma unroll
    for (int i = 0; i < 128; ++i) {
      float v = fmaf(-e1, f[64 + i], m[i]);
      m[i] = fmaf(-e2, f[192 + i], v);
    }
  }
  float* dst = Mc + ((size_t)cid * 128 + col) * 128;
#pragma unroll
  for (int i = 0; i < 128; ++i) dst[i] = m[i];
}

// offset column d_c: affine replay from h=0, one wave per chunk
__global__ __launch_bounds__(64) void scanB0(
    const float* __restrict__ Feat, float* __restrict__ dc) {
  const int cid = blockIdx.x;
  const int b = cid >> 5, ch = cid & 31;
  const int lane = threadIdx.x;
  float z = 0.f, y = 0.f;
  const int t0 = b * TT + ch * LCH;
  for (int t = t0; t < t0 + LCH; ++t) {
    const float* __restrict__ f = Feat + (size_t)t * FS;
    float s = f[lane], c1 = f[450 + lane];
    float k1z = f[64 + lane], k1y = f[128 + lane];
    float k2z = f[192 + lane], k2y = f[256 + lane];
    float bz = f[322 + lane], by = f[386 + lane];
    float b1 = f[320], b2 = f[321], c12 = f[514];
    float sz = s * z;
    float zn = fmaf(-c1, y, sz);
    float yn = fmaf(s, y, 0.1f * sz);
    float p = fmaf(k1y, yn, k1z * zn);
    float q = fmaf(k2y, yn, k2z * zn);
#pragma unroll
    for (int off = 32; off > 0; off >>= 1) {
      p += __shfl_xor(p, off, 64);
      q += __shfl_xor(q, off, 64);
    }
    float e1 = b1 * p;
    float d2 = fmaf(-c12, e1, q);
    float e2 = b2 * d2;
    z = fmaf(-e1, k1z, zn); z = fmaf(-e2, k2z, z); z += bz;
    y = fmaf(-e1, k1y, yn); y = fmaf(-e2, k2y, y); y += by;
  }
  dc[(size_t)cid * 128 + lane] = z;
  dc[(size_t)cid * 128 + 64 + lane] = y;
}

// sequential chunk combine: h <- M_c h + d_c, store h at chunk starts
__global__ __launch_bounds__(256) void scanB2(
    const float* __restrict__ Mc, const float* __restrict__ dc,
    float* __restrict__ hstart) {
  const int b = blockIdx.x;
  const int tid = threadIdx.x;
  const int i = tid & 127, jh = tid >> 7;    // split K over 2 halves
  __shared__ float h[128];
  __shared__ float red[2][128];
  if (tid < 128) h[tid] = 0.f;
  __syncthreads();
  float mreg[64];
  {
    const float* M0 = Mc + (size_t)(b * CH) * 16384;
#pragma unroll
    for (int j = 0; j < 64; ++j) mreg[j] = M0[(size_t)(jh * 64 + j) * 128 + i];
  }
  for (int c = 0; c < CH; ++c) {
    if (tid < 128) hstart[(size_t)(b * CH + c) * 128 + tid] = h[tid];
    float acc = 0.f;
#pragma unroll
    for (int j = 0; j < 64; ++j) acc = fmaf(mreg[j], h[jh * 64 + j], acc);
    red[jh][i] = acc;
    if (c + 1 < CH) {                        // prefetch next chunk's matrix
      const float* Mn = Mc + (size_t)(b * CH + c + 1) * 16384;
#pragma unroll
      for (int j = 0; j < 64; ++j) mreg[j] = Mn[(size_t)(jh * 64 + j) * 128 + i];
    }
    __syncthreads();
    if (tid < 128)
      h[tid] = red[0][tid] + red[1][tid] + dc[(size_t)(b * CH + c) * 128 + tid];
    __syncthreads();
  }
}

// replay within chunk from h_start, one wave per chunk, write hs
__global__ __launch_bounds__(64) void scanB3(
    const float* __restrict__ Feat, const float* __restrict__ hstart,
    float* __restrict__ hs) {
  const int cid = blockIdx.x;
  const int b = cid >> 5, ch = cid & 31;
  const int lane = threadIdx.x;
  float z = hstart[(size_t)cid * 128 + lane];
  float y = hstart[(size_t)cid * 128 + 64 + lane];
  const int t0 = b * TT + ch * LCH;
  for (int t = t0; t < t0 + LCH; ++t) {
    const float* __restrict__ f = Feat + (size_t)t * FS;
    float s = f[lane], c1 = f[450 + lane];
    float k1z = f[64 + lane], k1y = f[128 + lane];
    float k2z = f[192 + lane], k2y = f[256 + lane];
    float bz = f[322 + lane], by = f[386 + lane];
    float b1 = f[320], b2 = f[321], c12 = f[514];
    float sz = s * z;
    float zn = fmaf(-c1, y, sz);
    float yn = fmaf(s, y, 0.1f * sz);
    float p = fmaf(k1y, yn, k1z * zn);
    float q = fmaf(k2y, yn, k2z * zn);
#pragma unroll
    for (int off = 32; off > 0; off >>= 1) {
      p += __shfl_xor(p, off, 64);
      q += __shfl_xor(q, off, 64);
    }
    float e1 = b1 * p;
    float d2 = fmaf(-c12, e1, q);
    float e2 = b2 * d2;
    zn = fmaf(-e1, k1z, zn); zn = fmaf(-e2, k2z, zn); zn += bz;
    yn = fmaf(-e1, k1y, yn); yn = fmaf(-e2, k2y, yn); yn += by;
    hs[(size_t)t * 128 + lane] = zn;
    hs[(size_t)t * 128 + 64 + lane] = yn;
    z = zn; y = yn;
  }
}

// out = hs @ C^T + u*D : tile 64 tokens x 64 dims, K=128 in 2 halves
__global__ __launch_bounds__(256) void gemmC(
    const float* __restrict__ hs, const float* __restrict__ Cm,
    const float* __restrict__ u, const float* __restrict__ Dv,
    float* __restrict__ out) {
  __shared__ float as[64][68];   // [k][token]
  __shared__ float bs[64][68];   // [k][dim]
  const int tid = threadIdx.x;
  const int tx = tid & 15, ty = tid >> 4;
  const int t0 = blockIdx.x * 64;
  const int d0 = blockIdx.y * 64;
  float acc[4][4];
#pragma unroll
  for (int i = 0; i < 4; ++i)
#pragma unroll
    for (int j = 0; j < 4; ++j) acc[i][j] = 0.f;

  for (int k0 = 0; k0 < 128; k0 += 64) {
#pragma unroll
    for (int l = 0; l < 4; ++l) {
      int idx = tid + l * 256;           // 0..1023 over 64r x 16 float4
      int r = idx >> 4, c = (idx & 15) * 4;
      float4 v = *(const float4*)(hs + (size_t)(t0 + r) * 128 + k0 + c);
      as[c + 0][r] = v.x; as[c + 1][r] = v.y; as[c + 2][r] = v.z; as[c + 3][r] = v.w;
      float4 w = *(const float4*)(Cm + (size_t)(d0 + r) * 128 + k0 + c);
      bs[c + 0][r] = w.x; bs[c + 1][r] = w.y; bs[c + 2][r] = w.z; bs[c + 3][r] = w.w;
    }
    __syncthreads();
#pragma unroll
    for (int k = 0; k < 64; ++k) {
      float4 a = *(const float4*)&as[k][ty * 4];
      float4 b = *(const float4*)&bs[k][tx * 4];
      float av[4] = {a.x, a.y, a.z, a.w};
      float bv[4] = {b.x, b.y, b.z, b.w};
#pragma unroll
      for (int i = 0; i < 4; ++i)
#pragma unroll
        for (int j = 0; j < 4; ++j) acc[i][j] = fmaf(av[i], bv[j], acc[i][j]);
    }
    __syncthreads();
  }
#pragma unroll
  for (int i = 0; i < 4; ++i) {
    int row = t0 + ty * 4 + i;
    float4 uv = *(const float4*)(u + (size_t)row * DM + d0 + tx * 4);
    float4 dv = *(const float4*)(Dv + d0 + tx * 4);
    float4 o;
    o.x = fmaf(uv.x, dv.x, acc[i][0]);
    o.y = fmaf(uv.y, dv.y, acc[i][1]);
    o.z = fmaf(uv.z, dv.z, acc[i][2]);
    o.w = fmaf(uv.w, dv.w, acc[i][3]);
    *(float4*)(out + (size_t)row * DM + d0 + tx * 4) = o;
  }
}

extern "C" void kernel_launch(void* const* d_in, const int* in_sizes, int n_in,
                              void* d_out, int out_size, void* d_ws, size_t ws_size,
                              hipStream_t stream) {
  const float* u      = (const float*)d_in[0];
  const float* W_A    = (const float*)d_in[1];
  const float* b_A    = (const float*)d_in[2];
  const float* W_k    = (const float*)d_in[3];
  const float* b_k    = (const float*)d_in[4];
  const float* W_beta = (const float*)d_in[5];
  const float* b_beta = (const float*)d_in[6];
  const float* B_w    = (const float*)d_in[7];
  const float* B_b    = (const float*)d_in[8];
  const float* Cm     = (const float*)d_in[9];
  const float* Dv     = (const float*)d_in[10];
  float* out = (float*)d_out;
  char* ws = (char*)d_ws;
  // workspace carve-up (61.6 MB total)
  float* Wp     = (float*)(ws);                 // 512*1024*4       = 2,097,152
  float* bias   = (float*)(ws + 2097152);       // 512*4 (pad 4096)
  float* Feat   = (float*)(ws + 2101248);       // 16384*520*4      = 34,078,720
  float* Mc     = (float*)(ws + 36179968);      // 256*128*128*4    = 16,777,216
  float* dcv    = (float*)(ws + 52957184);      // 256*128*4        = 131,072
  float* hstart = (float*)(ws + 53088256);      // 256*128*4        = 131,072
  float* hsb    = (float*)(ws + 53219328);      // 16384*128*4      = 8,388,608

  packW<<<dim3(512), dim3(256), 0, stream>>>(W_A, b_A, W_k, b_k, W_beta, b_beta,
                                             B_w, B_b, Wp, bias);
  gemmA<<<dim3(128, 8), dim3(256), 0, stream>>>(u, Wp, Feat);
  postA<<<dim3(16384), dim3(64), 0, stream>>>(Feat, bias);
  scanB1<<<dim3(256), dim3(128), 0, stream>>>(Feat, Mc);
  scanB0<<<dim3(256), dim3(64), 0, stream>>>(Feat, dcv);
  scanB2<<<dim3(8), dim3(256), 0, stream>>>(Mc, dcv, hstart);
  scanB3<<<dim3(256), dim3(64), 0, stream>>>(Feat, hstart, hsb);
  gemmC<<<dim3(256, 16), dim3(256), 0, stream>>>(hsb, Cm, u, Dv, out);
}

// Round 4
// 571.562 us; speedup vs baseline: 2.8515x; 1.6487x over previous
//
#include <hip/hip_runtime.h>
#include <cmath>

// ---------------------------------------------------------------------------
// OHDeltaProductSSM: u(8,2048,1024) -> out(8,2048,1024), fp32.
// Pipeline:
//   packW  : gather weight rows into Wp[512][1024] (+bias[512]), scanB1 layout
//   gemmA  : Feat_raw[t][0..512) = u[t] . Wp[n]   (fp32 tiled GEMM)
//   postA  : per-token nonlinearity in-place in Feat
//   scanB1 : per (batch,chunk of 64): evolve 128 unit columns -> M_c.
//            512 thr/block = 128 cols x 4 quarters; each lane owns 32
//            m-elements (16 z/y pairs); dots via shfl_xor(1,2) over the
//            4-lane column group. Feat staged in LDS (4-step double buffer).
//   scanB0 : affine replay from h=0 per chunk (1 wave) -> d_c.
//   scanB2 : sequential combine over 32 chunks/batch -> hstart per chunk.
//   scanB3 : replay each chunk (1 wave, 64 steps) -> per-token states hs.
//   gemmC  : out[t][d] = hs[t] . C[d] + u[t][d]*D[d]
// Feat layout per token (FS=520 floats), all 16B-aligned blocks:
//   [0,64)=S  [64,128)=C1 (=DT*A*S; cols 64,65 carry raw beta preacts from
//   gemmA until postA overwrites)  [128,256)=k1  [256,384)=k2  [384,512)=Bt
//   [512]=b1 [513]=b2 [514]=c12
// ---------------------------------------------------------------------------

#define NTOK 16384
#define TT 2048
#define BB 8
#define DM 1024
#define FS 520
#define CH 32
#define LCH 64

__global__ __launch_bounds__(256) void packW(
    const float* __restrict__ W_A, const float* __restrict__ b_A,
    const float* __restrict__ W_k, const float* __restrict__ b_k,
    const float* __restrict__ W_beta, const float* __restrict__ b_beta,
    const float* __restrict__ B_w, const float* __restrict__ B_b,
    float* __restrict__ Wp, float* __restrict__ bias) {
  int r = blockIdx.x;          // 0..511
  int tid = threadIdx.x;       // 256 threads, one float4 each (1024 floats/row)
  const float* src = nullptr;
  float bv = 0.f;
  if (r < 64)       { src = W_A    + (size_t)r * DM;         bv = b_A[r]; }
  else if (r < 66)  { src = W_beta + (size_t)(r - 64) * DM;  bv = b_beta[r - 64]; }
  else if (r < 128) { src = nullptr; }                        // zero filler
  else if (r < 384) { src = W_k    + (size_t)(r - 128) * DM; bv = b_k[r - 128]; }
  else              { src = B_w    + (size_t)(r - 384) * DM; bv = B_b[r - 384]; }
  float4* dst = (float4*)(Wp + (size_t)r * DM);
  if (src) dst[tid] = ((const float4*)src)[tid];
  else     dst[tid] = make_float4(0.f, 0.f, 0.f, 0.f);
  if (tid == 0) bias[r] = bv;
}

// Feat_raw = u @ Wp^T : tile 128 tokens x 64 feats, BK=32
__global__ __launch_bounds__(256) void gemmA(
    const float* __restrict__ u, const float* __restrict__ Wp,
    float* __restrict__ Feat) {
  __shared__ float us[32][132];
  __shared__ float wsm[32][68];
  const int tid = threadIdx.x;
  const int tx = tid & 15, ty = tid >> 4;
  const int m0 = blockIdx.x * 128;
  const int n0 = blockIdx.y * 64;
  float acc[8][4];
#pragma unroll
  for (int i = 0; i < 8; ++i)
#pragma unroll
    for (int j = 0; j < 4; ++j) acc[i][j] = 0.f;

  for (int k0 = 0; k0 < DM; k0 += 32) {
#pragma unroll
    for (int l = 0; l < 4; ++l) {        // u tile: 128x32
      int idx = tid + l * 256;
      int r = idx >> 3, c = (idx & 7) * 4;
      float4 v = *(const float4*)(u + (size_t)(m0 + r) * DM + k0 + c);
      us[c + 0][r] = v.x; us[c + 1][r] = v.y; us[c + 2][r] = v.z; us[c + 3][r] = v.w;
    }
#pragma unroll
    for (int l = 0; l < 2; ++l) {        // W tile: 64x32
      int idx = tid + l * 256;
      int r = idx >> 3, c = (idx & 7) * 4;
      float4 v = *(const float4*)(Wp + (size_t)(n0 + r) * DM + k0 + c);
      wsm[c + 0][r] = v.x; wsm[c + 1][r] = v.y; wsm[c + 2][r] = v.z; wsm[c + 3][r] = v.w;
    }
    __syncthreads();
#pragma unroll
    for (int k = 0; k < 32; ++k) {
      float4 b  = *(const float4*)&wsm[k][tx * 4];
      float4 a0 = *(const float4*)&us[k][ty * 8];
      float4 a1 = *(const float4*)&us[k][ty * 8 + 4];
      float av[8] = {a0.x, a0.y, a0.z, a0.w, a1.x, a1.y, a1.z, a1.w};
      float bv[4] = {b.x, b.y, b.z, b.w};
#pragma unroll
      for (int i = 0; i < 8; ++i)
#pragma unroll
        for (int j = 0; j < 4; ++j) acc[i][j] = fmaf(av[i], bv[j], acc[i][j]);
    }
    __syncthreads();
  }
#pragma unroll
  for (int i = 0; i < 8; ++i) {
    float4 v = make_float4(acc[i][0], acc[i][1], acc[i][2], acc[i][3]);
    *(float4*)(Feat + (size_t)(m0 + ty * 8 + i) * FS + n0 + tx * 4) = v;
  }
}

__device__ inline float wave_sum(float v) {
#pragma unroll
  for (int off = 32; off > 0; off >>= 1) v += __shfl_xor(v, off, 64);
  return v;
}

// per-token nonlinearity, one wave per token, in-place in Feat (new layout)
__global__ __launch_bounds__(64) void postA(float* __restrict__ Feat,
                                            const float* __restrict__ bias) {
  const int t = blockIdx.x, lane = threadIdx.x;
  float* f = Feat + (size_t)t * FS;
  float braw = f[64 + lane];            // lanes 0,1 carry beta preacts
  // A -> S, C1
  float a = f[lane] + bias[lane];
  a = fminf(fmaxf(a, 0.f), 100.f);
  float S = 1.f / (1.f + 0.01f * a);
  f[lane] = S;
  f[64 + lane] = 0.1f * a * S;          // C1 overwrites beta slots (saved)
  // k1
  float k10 = f[128 + lane] + bias[128 + lane];
  float k11 = f[192 + lane] + bias[192 + lane];
  float n1 = wave_sum(k10 * k10 + k11 * k11);
  float inv1 = 1.f / fmaxf(sqrtf(n1), 1e-12f);
  k10 *= inv1; k11 *= inv1;
  f[128 + lane] = k10; f[192 + lane] = k11;
  // k2
  float k20 = f[256 + lane] + bias[256 + lane];
  float k21 = f[320 + lane] + bias[320 + lane];
  float n2 = wave_sum(k20 * k20 + k21 * k21);
  float inv2 = 1.f / fmaxf(sqrtf(n2), 1e-12f);
  k20 *= inv2; k21 *= inv2;
  f[256 + lane] = k20; f[320 + lane] = k21;
  // c12
  float c12 = wave_sum(k10 * k20 + k11 * k21);
  if (lane == 0) f[514] = c12;
  // beta
  if (lane < 2) {
    float x = braw + bias[64 + lane];
    f[512 + lane] = 2.f / (1.f + expf(-x));
  }
  // Bt bias add
  f[384 + lane] += bias[384 + lane];
  f[448 + lane] += bias[448 + lane];
}

// chunk transition matrices. 512 threads: col = tid>>2, quarter q = tid&3.
// Lane owns m[i], m[i+64] for i in [16q, 16q+16). Feat staged in LDS,
// double-buffered 4-step groups (rows contiguous since stride == FS).
__global__ __launch_bounds__(512, 2) void scanB1(
    const float* __restrict__ Feat, float* __restrict__ Mc) {
  const int cid = blockIdx.x;              // 0..255 = b*32 + chunk
  const int t0 = (cid >> 5) * TT + (cid & 31) * LCH;
  const int tid = threadIdx.x;
  const int col = tid >> 2, q = tid & 3;
  const int i0 = q * 16;
  __shared__ float fb[2][4 * FS];          // 2 x 8320 B
  float mz[16], my[16];
#pragma unroll
  for (int j = 0; j < 16; ++j) {
    mz[j] = (i0 + j == col) ? 1.f : 0.f;
    my[j] = (64 + i0 + j == col) ? 1.f : 0.f;
  }
  {  // preload group 0 (2080 floats = 520 float4, coalesced)
    const float4* src = (const float4*)(Feat + (size_t)t0 * FS);
    for (int v = tid; v < FS; v += 512) ((float4*)fb[0])[v] = src[v];
  }
  __syncthreads();
  for (int g = 0; g < 16; ++g) {
    const int cur = g & 1;
    float4 pf0, pf1;
    const bool has2 = tid < (FS - 512);
    if (g < 15) {                          // prefetch next group into regs
      const float4* src = (const float4*)(Feat + (size_t)(t0 + (g + 1) * 4) * FS);
      pf0 = src[tid];
      if (has2) pf1 = src[tid + 512];
    }
#pragma unroll
    for (int s = 0; s < 4; ++s) {
      const float* f = fb[cur] + s * FS;
      float sj[16], cj[16], k1z[16], k1y[16], k2z[16], k2y[16];
#pragma unroll
      for (int v = 0; v < 4; ++v) {
        *(float4*)&sj[4 * v]  = *(const float4*)(f + i0 + 4 * v);
        *(float4*)&cj[4 * v]  = *(const float4*)(f + 64 + i0 + 4 * v);
        *(float4*)&k1z[4 * v] = *(const float4*)(f + 128 + i0 + 4 * v);
        *(float4*)&k1y[4 * v] = *(const float4*)(f + 192 + i0 + 4 * v);
        *(float4*)&k2z[4 * v] = *(const float4*)(f + 256 + i0 + 4 * v);
        *(float4*)&k2y[4 * v] = *(const float4*)(f + 320 + i0 + 4 * v);
      }
      float4 sc = *(const float4*)(f + 512);   // b1, b2, c12, pad
      float p = 0.f, r2 = 0.f;
#pragma unroll
      for (int j = 0; j < 16; ++j) {          // rotate + partial dots
        float s0 = sj[j], c1 = cj[j];
        float z = mz[j], y = my[j];
        float sz = s0 * z;
        z = fmaf(-c1, y, sz);
        y = fmaf(s0, y, 0.1f * sz);
        mz[j] = z; my[j] = y;
        p  = fmaf(k1z[j], z, p);  p  = fmaf(k1y[j], y, p);
        r2 = fmaf(k2z[j], z, r2); r2 = fmaf(k2y[j], y, r2);
      }
      p  += __shfl_xor(p, 1, 64);  p  += __shfl_xor(p, 2, 64);
      r2 += __shfl_xor(r2, 1, 64); r2 += __shfl_xor(r2, 2, 64);
      float e1 = sc.x * p;
      float e2 = sc.y * fmaf(-sc.z, e1, r2);
#pragma unroll
      for (int j = 0; j < 16; ++j) {          // rank-2 update
        float z = fmaf(-e1, k1z[j], mz[j]);
        mz[j] = fmaf(-e2, k2z[j], z);
        float y = fmaf(-e1, k1y[j], my[j]);
        my[j] = fmaf(-e2, k2y[j], y);
      }
    }
    if (g < 15) {
      ((float4*)fb[1 - cur])[tid] = pf0;
      if (has2) ((float4*)fb[1 - cur])[tid + 512] = pf1;
    }
    __syncthreads();
  }
  float* dst = Mc + ((size_t)cid * 128 + col) * 128;
#pragma unroll
  for (int v = 0; v < 4; ++v)
    *(float4*)(dst + i0 + 4 * v) = *(float4*)&mz[4 * v];
#pragma unroll
  for (int v = 0; v < 4; ++v)
    *(float4*)(dst + 64 + i0 + 4 * v) = *(float4*)&my[4 * v];
}

// offset column d_c: affine replay from h=0, one wave per chunk
__global__ __launch_bounds__(64) void scanB0(
    const float* __restrict__ Feat, float* __restrict__ dc) {
  const int cid = blockIdx.x;
  const int b = cid >> 5, ch = cid & 31;
  const int lane = threadIdx.x;
  float z = 0.f, y = 0.f;
  const int t0 = b * TT + ch * LCH;
  for (int t = t0; t < t0 + LCH; ++t) {
    const float* __restrict__ f = Feat + (size_t)t * FS;
    float s = f[lane], c1 = f[64 + lane];
    float k1z = f[128 + lane], k1y = f[192 + lane];
    float k2z = f[256 + lane], k2y = f[320 + lane];
    float bz = f[384 + lane], by = f[448 + lane];
    float b1 = f[512], b2 = f[513], c12 = f[514];
    float sz = s * z;
    float zn = fmaf(-c1, y, sz);
    float yn = fmaf(s, y, 0.1f * sz);
    float p = fmaf(k1y, yn, k1z * zn);
    float qq = fmaf(k2y, yn, k2z * zn);
#pragma unroll
    for (int off = 32; off > 0; off >>= 1) {
      p += __shfl_xor(p, off, 64);
      qq += __shfl_xor(qq, off, 64);
    }
    float e1 = b1 * p;
    float d2 = fmaf(-c12, e1, qq);
    float e2 = b2 * d2;
    z = fmaf(-e1, k1z, zn); z = fmaf(-e2, k2z, z); z += bz;
    y = fmaf(-e1, k1y, yn); y = fmaf(-e2, k2y, y); y += by;
  }
  dc[(size_t)cid * 128 + lane] = z;
  dc[(size_t)cid * 128 + 64 + lane] = y;
}

// sequential chunk combine: h <- M_c h + d_c, store h at chunk starts
__global__ __launch_bounds__(256) void scanB2(
    const float* __restrict__ Mc, const float* __restrict__ dc,
    float* __restrict__ hstart) {
  const int b = blockIdx.x;
  const int tid = threadIdx.x;
  const int i = tid & 127, jh = tid >> 7;    // split K over 2 halves
  __shared__ float h[128];
  __shared__ float red[2][128];
  if (tid < 128) h[tid] = 0.f;
  __syncthreads();
  float mreg[64];
  {
    const float* M0 = Mc + (size_t)(b * CH) * 16384;
#pragma unroll
    for (int j = 0; j < 64; ++j) mreg[j] = M0[(size_t)(jh * 64 + j) * 128 + i];
  }
  for (int c = 0; c < CH; ++c) {
    if (tid < 128) hstart[(size_t)(b * CH + c) * 128 + tid] = h[tid];
    float acc = 0.f;
#pragma unroll
    for (int j = 0; j < 64; ++j) acc = fmaf(mreg[j], h[jh * 64 + j], acc);
    red[jh][i] = acc;
    if (c + 1 < CH) {                        // prefetch next chunk's matrix
      const float* Mn = Mc + (size_t)(b * CH + c + 1) * 16384;
#pragma unroll
      for (int j = 0; j < 64; ++j) mreg[j] = Mn[(size_t)(jh * 64 + j) * 128 + i];
    }
    __syncthreads();
    if (tid < 128)
      h[tid] = red[0][tid] + red[1][tid] + dc[(size_t)(b * CH + c) * 128 + tid];
    __syncthreads();
  }
}

// replay within chunk from h_start, one wave per chunk, write hs
__global__ __launch_bounds__(64) void scanB3(
    const float* __restrict__ Feat, const float* __restrict__ hstart,
    float* __restrict__ hs) {
  const int cid = blockIdx.x;
  const int b = cid >> 5, ch = cid & 31;
  const int lane = threadIdx.x;
  float z = hstart[(size_t)cid * 128 + lane];
  float y = hstart[(size_t)cid * 128 + 64 + lane];
  const int t0 = b * TT + ch * LCH;
  for (int t = t0; t < t0 + LCH; ++t) {
    const float* __restrict__ f = Feat + (size_t)t * FS;
    float s = f[lane], c1 = f[64 + lane];
    float k1z = f[128 + lane], k1y = f[192 + lane];
    float k2z = f[256 + lane], k2y = f[320 + lane];
    float bz = f[384 + lane], by = f[448 + lane];
    float b1 = f[512], b2 = f[513], c12 = f[514];
    float sz = s * z;
    float zn = fmaf(-c1, y, sz);
    float yn = fmaf(s, y, 0.1f * sz);
    float p = fmaf(k1y, yn, k1z * zn);
    float qq = fmaf(k2y, yn, k2z * zn);
#pragma unroll
    for (int off = 32; off > 0; off >>= 1) {
      p += __shfl_xor(p, off, 64);
      qq += __shfl_xor(qq, off, 64);
    }
    float e1 = b1 * p;
    float d2 = fmaf(-c12, e1, qq);
    float e2 = b2 * d2;
    zn = fmaf(-e1, k1z, zn); zn = fmaf(-e2, k2z, zn); zn += bz;
    yn = fmaf(-e1, k1y, yn); yn = fmaf(-e2, k2y, yn); yn += by;
    hs[(size_t)t * 128 + lane] = zn;
    hs[(size_t)t * 128 + 64 + lane] = yn;
    z = zn; y = yn;
  }
}

// out = hs @ C^T + u*D : tile 64 tokens x 64 dims, K=128 in 2 halves
__global__ __launch_bounds__(256) void gemmC(
    const float* __restrict__ hs, const float* __restrict__ Cm,
    const float* __restrict__ u, const float* __restrict__ Dv,
    float* __restrict__ out) {
  __shared__ float as[64][68];   // [k][token]
  __shared__ float bs[64][68];   // [k][dim]
  const int tid = threadIdx.x;
  const int tx = tid & 15, ty = tid >> 4;
  const int t0 = blockIdx.x * 64;
  const int d0 = blockIdx.y * 64;
  float acc[4][4];
#pragma unroll
  for (int i = 0; i < 4; ++i)
#pragma unroll
    for (int j = 0; j < 4; ++j) acc[i][j] = 0.f;

  for (int k0 = 0; k0 < 128; k0 += 64) {
#pragma unroll
    for (int l = 0; l < 4; ++l) {
      int idx = tid + l * 256;           // 0..1023 over 64r x 16 float4
      int r = idx >> 4, c = (idx & 15) * 4;
      float4 v = *(const float4*)(hs + (size_t)(t0 + r) * 128 + k0 + c);
      as[c + 0][r] = v.x; as[c + 1][r] = v.y; as[c + 2][r] = v.z; as[c + 3][r] = v.w;
      float4 w = *(const float4*)(Cm + (size_t)(d0 + r) * 128 + k0 + c);
      bs[c + 0][r] = w.x; bs[c + 1][r] = w.y; bs[c + 2][r] = w.z; bs[c + 3][r] = w.w;
    }
    __syncthreads();
#pragma unroll
    for (int k = 0; k < 64; ++k) {
      float4 a = *(const float4*)&as[k][ty * 4];
      float4 b = *(const float4*)&bs[k][tx * 4];
      float av[4] = {a.x, a.y, a.z, a.w};
      float bv[4] = {b.x, b.y, b.z, b.w};
#pragma unroll
      for (int i = 0; i < 4; ++i)
#pragma unroll
        for (int j = 0; j < 4; ++j) acc[i][j] = fmaf(av[i], bv[j], acc[i][j]);
    }
    __syncthreads();
  }
#pragma unroll
  for (int i = 0; i < 4; ++i) {
    int row = t0 + ty * 4 + i;
    float4 uv = *(const float4*)(u + (size_t)row * DM + d0 + tx * 4);
    float4 dv = *(const float4*)(Dv + d0 + tx * 4);
    float4 o;
    o.x = fmaf(uv.x, dv.x, acc[i][0]);
    o.y = fmaf(uv.y, dv.y, acc[i][1]);
    o.z = fmaf(uv.z, dv.z, acc[i][2]);
    o.w = fmaf(uv.w, dv.w, acc[i][3]);
    *(float4*)(out + (size_t)row * DM + d0 + tx * 4) = o;
  }
}

extern "C" void kernel_launch(void* const* d_in, const int* in_sizes, int n_in,
                              void* d_out, int out_size, void* d_ws, size_t ws_size,
                              hipStream_t stream) {
  const float* u      = (const float*)d_in[0];
  const float* W_A    = (const float*)d_in[1];
  const float* b_A    = (const float*)d_in[2];
  const float* W_k    = (const float*)d_in[3];
  const float* b_k    = (const float*)d_in[4];
  const float* W_beta = (const float*)d_in[5];
  const float* b_beta = (const float*)d_in[6];
  const float* B_w    = (const float*)d_in[7];
  const float* B_b    = (const float*)d_in[8];
  const float* Cm     = (const float*)d_in[9];
  const float* Dv     = (const float*)d_in[10];
  float* out = (float*)d_out;
  char* ws = (char*)d_ws;
  // workspace carve-up (61.6 MB total)
  float* Wp     = (float*)(ws);                 // 512*1024*4       = 2,097,152
  float* bias   = (float*)(ws + 2097152);       // 512*4 (pad 4096)
  float* Feat   = (float*)(ws + 2101248);       // 16384*520*4      = 34,078,720
  float* Mc     = (float*)(ws + 36179968);      // 256*128*128*4    = 16,777,216
  float* dcv    = (float*)(ws + 52957184);      // 256*128*4        = 131,072
  float* hstart = (float*)(ws + 53088256);      // 256*128*4        = 131,072
  float* hsb    = (float*)(ws + 53219328);      // 16384*128*4      = 8,388,608

  packW<<<dim3(512), dim3(256), 0, stream>>>(W_A, b_A, W_k, b_k, W_beta, b_beta,
                                             B_w, B_b, Wp, bias);
  gemmA<<<dim3(128, 8), dim3(256), 0, stream>>>(u, Wp, Feat);
  postA<<<dim3(16384), dim3(64), 0, stream>>>(Feat, bias);
  scanB1<<<dim3(256), dim3(512), 0, stream>>>(Feat, Mc);
  scanB0<<<dim3(256), dim3(64), 0, stream>>>(Feat, dcv);
  scanB2<<<dim3(8), dim3(256), 0, stream>>>(Mc, dcv, hstart);
  scanB3<<<dim3(256), dim3(64), 0, stream>>>(Feat, hstart, hsb);
  gemmC<<<dim3(256, 16), dim3(256), 0, stream>>>(hsb, Cm, u, Dv, out);
}

// Round 5
// 561.631 us; speedup vs baseline: 2.9019x; 1.0177x over previous
//
#include <hip/hip_runtime.h>
#include <cmath>

// ---------------------------------------------------------------------------
// OHDeltaProductSSM: u(8,2048,1024) -> out(8,2048,1024), fp32.
// Pipeline:
//   packW  : weight rows -> Wp[448][1024] (+bias[450])
//   transK : generic 64x64-tiled transpose: Wp->WpT[1024][448], Cm->CmT[128][1024]
//   gemmA  : Feat_raw[t][0..448) = u[t] . Wp  — A-tile [m][k] direct copy,
//            B-tile [k][n] from WpT direct copy, k4-vectorized inner loop.
//            No LDS transpose scatter (round-4: 1.9e7 bank-conflict cycles).
//   postA  : per-token nonlinearity in-place + beta = 2*sigmoid(u.W_beta+b)
//   scanB1 : per (batch,chunk of 64): 128 unit columns -> M_c. 512 thr:
//            128 cols x 4 quarters, dots via shfl_xor(1,2). LDS-staged Feat.
//   scanB0 : affine replay from h=0 per chunk (1 wave) -> d_c.
//   scanB2 : sequential combine over 32 chunks/batch -> hstart.
//   scanB3 : replay chunks (1 wave, 64 steps) -> per-token states hs.
//   gemmC  : out = hs . C^T + u*D — same direct-copy tile structure via CmT.
// Feat layout per token (FS=520 floats):
//   [0,64)=S  [64,192)=k1  [192,320)=k2  [320,448)=Bt  [448,512)=C1
//   [512]=b1 [513]=b2 [514]=c12
// ---------------------------------------------------------------------------

#define NTOK 16384
#define TT 2048
#define BB 8
#define DM 1024
#define FS 520
#define CH 32
#define LCH 64
#define NW 448   // packed weight rows

__global__ __launch_bounds__(256) void packW(
    const float* __restrict__ W_A, const float* __restrict__ b_A,
    const float* __restrict__ W_k, const float* __restrict__ b_k,
    const float* __restrict__ b_beta,
    const float* __restrict__ B_w, const float* __restrict__ B_b,
    float* __restrict__ Wp, float* __restrict__ bias) {
  int r = blockIdx.x;          // 0..447
  int tid = threadIdx.x;
  const float* src;
  float bv;
  if (r < 64)       { src = W_A + (size_t)r * DM;         bv = b_A[r]; }
  else if (r < 320) { src = W_k + (size_t)(r - 64) * DM;  bv = b_k[r - 64]; }
  else              { src = B_w + (size_t)(r - 320) * DM; bv = B_b[r - 320]; }
  ((float4*)(Wp + (size_t)r * DM))[tid] = ((const float4*)src)[tid];
  if (tid == 0) bias[r] = bv;
  if (r == 0 && tid < 2) bias[448 + tid] = b_beta[tid];
}

// generic transpose: src[M][N] -> dst[N][M], 64x64 tiles, M,N multiples of 64
__global__ __launch_bounds__(256) void transK(
    const float* __restrict__ src, float* __restrict__ dst, int M, int N) {
  __shared__ float tile[64][68];
  const int m0 = blockIdx.x * 64, n0 = blockIdx.y * 64;
  const int tid = threadIdx.x;
#pragma unroll
  for (int l = 0; l < 4; ++l) {
    int idx = tid + l * 256;
    int r = idx >> 4, c4 = (idx & 15) * 4;
    float4 v = *(const float4*)(src + (size_t)(m0 + r) * N + n0 + c4);
    tile[r][c4 + 0] = v.x; tile[r][c4 + 1] = v.y;
    tile[r][c4 + 2] = v.z; tile[r][c4 + 3] = v.w;
  }
  __syncthreads();
#pragma unroll
  for (int l = 0; l < 4; ++l) {
    int idx = tid + l * 256;
    int c = idx >> 4, r4 = (idx & 15) * 4;
    float4 w = make_float4(tile[r4 + 0][c], tile[r4 + 1][c],
                           tile[r4 + 2][c], tile[r4 + 3][c]);
    *(float4*)(dst + (size_t)(n0 + c) * M + m0 + r4) = w;
  }
}

// Feat_raw = u @ Wp^T : tile 128 tokens x 64 feats, BK=32, k4 inner loop.
__global__ __launch_bounds__(256) void gemmA(
    const float* __restrict__ u, const float* __restrict__ WpT,
    float* __restrict__ Feat) {
  __shared__ float us2[128][36];   // [m][k], rows 144B (16B mult)
  __shared__ float wsm[32][68];    // [k][n], rows 272B
  const int tid = threadIdx.x;
  const int tx = tid & 15, ty = tid >> 4;
  const int m0 = blockIdx.x * 128;
  const int n0 = blockIdx.y * 64;
  float acc[8][4];
#pragma unroll
  for (int i = 0; i < 8; ++i)
#pragma unroll
    for (int j = 0; j < 4; ++j) acc[i][j] = 0.f;

  for (int k0 = 0; k0 < DM; k0 += 32) {
#pragma unroll
    for (int l = 0; l < 4; ++l) {        // A tile: 128 rows x 8 float4 (k)
      int idx = tid + l * 256;
      int r = idx >> 3, c4 = (idx & 7) * 4;
      float4 v = *(const float4*)(u + (size_t)(m0 + r) * DM + k0 + c4);
      *(float4*)&us2[r][c4] = v;
    }
#pragma unroll
    for (int l = 0; l < 2; ++l) {        // B tile: 32 rows(k) x 16 float4 (n)
      int idx = tid + l * 256;
      int k = idx >> 4, c4 = (idx & 15) * 4;
      float4 v = *(const float4*)(WpT + (size_t)(k0 + k) * NW + n0 + c4);
      *(float4*)&wsm[k][c4] = v;
    }
    __syncthreads();
#pragma unroll
    for (int k4 = 0; k4 < 8; ++k4) {
      float4 bq0 = *(const float4*)&wsm[4 * k4 + 0][tx * 4];
      float4 bq1 = *(const float4*)&wsm[4 * k4 + 1][tx * 4];
      float4 bq2 = *(const float4*)&wsm[4 * k4 + 2][tx * 4];
      float4 bq3 = *(const float4*)&wsm[4 * k4 + 3][tx * 4];
#pragma unroll
      for (int i = 0; i < 8; ++i) {
        float4 a = *(const float4*)&us2[ty * 8 + i][4 * k4];
        acc[i][0] = fmaf(a.x, bq0.x, acc[i][0]);
        acc[i][1] = fmaf(a.x, bq0.y, acc[i][1]);
        acc[i][2] = fmaf(a.x, bq0.z, acc[i][2]);
        acc[i][3] = fmaf(a.x, bq0.w, acc[i][3]);
        acc[i][0] = fmaf(a.y, bq1.x, acc[i][0]);
        acc[i][1] = fmaf(a.y, bq1.y, acc[i][1]);
        acc[i][2] = fmaf(a.y, bq1.z, acc[i][2]);
        acc[i][3] = fmaf(a.y, bq1.w, acc[i][3]);
        acc[i][0] = fmaf(a.z, bq2.x, acc[i][0]);
        acc[i][1] = fmaf(a.z, bq2.y, acc[i][1]);
        acc[i][2] = fmaf(a.z, bq2.z, acc[i][2]);
        acc[i][3] = fmaf(a.z, bq2.w, acc[i][3]);
        acc[i][0] = fmaf(a.w, bq3.x, acc[i][0]);
        acc[i][1] = fmaf(a.w, bq3.y, acc[i][1]);
        acc[i][2] = fmaf(a.w, bq3.z, acc[i][2]);
        acc[i][3] = fmaf(a.w, bq3.w, acc[i][3]);
      }
    }
    __syncthreads();
  }
#pragma unroll
  for (int i = 0; i < 8; ++i) {
    float4 v = make_float4(acc[i][0], acc[i][1], acc[i][2], acc[i][3]);
    *(float4*)(Feat + (size_t)(m0 + ty * 8 + i) * FS + n0 + tx * 4) = v;
  }
}

__device__ inline float wave_sum(float v) {
#pragma unroll
  for (int off = 32; off > 0; off >>= 1) v += __shfl_xor(v, off, 64);
  return v;
}

// per-token nonlinearity, one wave per token, in-place in Feat
__global__ __launch_bounds__(64) void postA(float* __restrict__ Feat,
                                            const float* __restrict__ bias,
                                            const float* __restrict__ u,
                                            const float* __restrict__ Wb) {
  const int t = blockIdx.x, lane = threadIdx.x;
  float* f = Feat + (size_t)t * FS;
  // beta preactivations: u[t] . W_beta[j]
  float s0 = 0.f, s1 = 0.f;
#pragma unroll
  for (int j = 0; j < 4; ++j) {
    float4 uv = *(const float4*)(u + (size_t)t * DM + j * 256 + lane * 4);
    float4 w0 = *(const float4*)(Wb + j * 256 + lane * 4);
    float4 w1 = *(const float4*)(Wb + DM + j * 256 + lane * 4);
    s0 = fmaf(uv.x, w0.x, s0); s0 = fmaf(uv.y, w0.y, s0);
    s0 = fmaf(uv.z, w0.z, s0); s0 = fmaf(uv.w, w0.w, s0);
    s1 = fmaf(uv.x, w1.x, s1); s1 = fmaf(uv.y, w1.y, s1);
    s1 = fmaf(uv.z, w1.z, s1); s1 = fmaf(uv.w, w1.w, s1);
  }
  s0 = wave_sum(s0); s1 = wave_sum(s1);
  // A -> S, C1
  float a = f[lane] + bias[lane];
  a = fminf(fmaxf(a, 0.f), 100.f);
  float S = 1.f / (1.f + 0.01f * a);
  f[lane] = S;
  f[448 + lane] = 0.1f * a * S;
  // k1
  float k10 = f[64 + lane] + bias[64 + lane];
  float k11 = f[128 + lane] + bias[128 + lane];
  float n1 = wave_sum(k10 * k10 + k11 * k11);
  float inv1 = 1.f / fmaxf(sqrtf(n1), 1e-12f);
  k10 *= inv1; k11 *= inv1;
  f[64 + lane] = k10; f[128 + lane] = k11;
  // k2
  float k20 = f[192 + lane] + bias[192 + lane];
  float k21 = f[256 + lane] + bias[256 + lane];
  float n2 = wave_sum(k20 * k20 + k21 * k21);
  float inv2 = 1.f / fmaxf(sqrtf(n2), 1e-12f);
  k20 *= inv2; k21 *= inv2;
  f[192 + lane] = k20; f[256 + lane] = k21;
  // c12
  float c12 = wave_sum(k10 * k20 + k11 * k21);
  if (lane == 0) {
    f[512] = 2.f / (1.f + expf(-(s0 + bias[448])));
    f[513] = 2.f / (1.f + expf(-(s1 + bias[449])));
    f[514] = c12;
  }
  // Bt bias add
  f[320 + lane] += bias[320 + lane];
  f[384 + lane] += bias[384 + lane];
}

// chunk transition matrices. 512 threads: col = tid>>2, quarter q = tid&3.
__global__ __launch_bounds__(512, 2) void scanB1(
    const float* __restrict__ Feat, float* __restrict__ Mc) {
  const int cid = blockIdx.x;              // 0..255 = b*32 + chunk
  const int t0 = (cid >> 5) * TT + (cid & 31) * LCH;
  const int tid = threadIdx.x;
  const int col = tid >> 2, q = tid & 3;
  const int i0 = q * 16;
  __shared__ float fb[2][4 * FS];
  float mz[16], my[16];
#pragma unroll
  for (int j = 0; j < 16; ++j) {
    mz[j] = (i0 + j == col) ? 1.f : 0.f;
    my[j] = (64 + i0 + j == col) ? 1.f : 0.f;
  }
  {
    const float4* src = (const float4*)(Feat + (size_t)t0 * FS);
    for (int v = tid; v < FS; v += 512) ((float4*)fb[0])[v] = src[v];
  }
  __syncthreads();
  for (int g = 0; g < 16; ++g) {
    const int cur = g & 1;
    float4 pf0, pf1;
    const bool has2 = tid < (FS - 512);
    if (g < 15) {
      const float4* src = (const float4*)(Feat + (size_t)(t0 + (g + 1) * 4) * FS);
      pf0 = src[tid];
      if (has2) pf1 = src[tid + 512];
    }
#pragma unroll
    for (int s = 0; s < 4; ++s) {
      const float* f = fb[cur] + s * FS;
      float sj[16], cj[16], k1z[16], k1y[16], k2z[16], k2y[16];
#pragma unroll
      for (int v = 0; v < 4; ++v) {
        *(float4*)&sj[4 * v]  = *(const float4*)(f + i0 + 4 * v);
        *(float4*)&cj[4 * v]  = *(const float4*)(f + 448 + i0 + 4 * v);
        *(float4*)&k1z[4 * v] = *(const float4*)(f + 64 + i0 + 4 * v);
        *(float4*)&k1y[4 * v] = *(const float4*)(f + 128 + i0 + 4 * v);
        *(float4*)&k2z[4 * v] = *(const float4*)(f + 192 + i0 + 4 * v);
        *(float4*)&k2y[4 * v] = *(const float4*)(f + 256 + i0 + 4 * v);
      }
      float4 sc = *(const float4*)(f + 512);   // b1, b2, c12, pad
      float p = 0.f, r2 = 0.f;
#pragma unroll
      for (int j = 0; j < 16; ++j) {
        float s0 = sj[j], c1 = cj[j];
        float z = mz[j], y = my[j];
        float sz = s0 * z;
        z = fmaf(-c1, y, sz);
        y = fmaf(s0, y, 0.1f * sz);
        mz[j] = z; my[j] = y;
        p  = fmaf(k1z[j], z, p);  p  = fmaf(k1y[j], y, p);
        r2 = fmaf(k2z[j], z, r2); r2 = fmaf(k2y[j], y, r2);
      }
      p  += __shfl_xor(p, 1, 64);  p  += __shfl_xor(p, 2, 64);
      r2 += __shfl_xor(r2, 1, 64); r2 += __shfl_xor(r2, 2, 64);
      float e1 = sc.x * p;
      float e2 = sc.y * fmaf(-sc.z, e1, r2);
#pragma unroll
      for (int j = 0; j < 16; ++j) {
        float z = fmaf(-e1, k1z[j], mz[j]);
        mz[j] = fmaf(-e2, k2z[j], z);
        float y = fmaf(-e1, k1y[j], my[j]);
        my[j] = fmaf(-e2, k2y[j], y);
      }
    }
    if (g < 15) {
      ((float4*)fb[1 - cur])[tid] = pf0;
      if (has2) ((float4*)fb[1 - cur])[tid + 512] = pf1;
    }
    __syncthreads();
  }
  float* dst = Mc + ((size_t)cid * 128 + col) * 128;
#pragma unroll
  for (int v = 0; v < 4; ++v)
    *(float4*)(dst + i0 + 4 * v) = *(float4*)&mz[4 * v];
#pragma unroll
  for (int v = 0; v < 4; ++v)
    *(float4*)(dst + 64 + i0 + 4 * v) = *(float4*)&my[4 * v];
}

// offset column d_c: affine replay from h=0, one wave per chunk
__global__ __launch_bounds__(64) void scanB0(
    const float* __restrict__ Feat, float* __restrict__ dc) {
  const int cid = blockIdx.x;
  const int lane = threadIdx.x;
  float z = 0.f, y = 0.f;
  const int t0 = (cid >> 5) * TT + (cid & 31) * LCH;
  for (int t = t0; t < t0 + LCH; ++t) {
    const float* __restrict__ f = Feat + (size_t)t * FS;
    float s = f[lane], c1 = f[448 + lane];
    float k1z = f[64 + lane], k1y = f[128 + lane];
    float k2z = f[192 + lane], k2y = f[256 + lane];
    float bz = f[320 + lane], by = f[384 + lane];
    float b1 = f[512], b2 = f[513], c12 = f[514];
    float sz = s * z;
    float zn = fmaf(-c1, y, sz);
    float yn = fmaf(s, y, 0.1f * sz);
    float p = fmaf(k1y, yn, k1z * zn);
    float qq = fmaf(k2y, yn, k2z * zn);
#pragma unroll
    for (int off = 32; off > 0; off >>= 1) {
      p += __shfl_xor(p, off, 64);
      qq += __shfl_xor(qq, off, 64);
    }
    float e1 = b1 * p;
    float d2 = fmaf(-c12, e1, qq);
    float e2 = b2 * d2;
    z = fmaf(-e1, k1z, zn); z = fmaf(-e2, k2z, z); z += bz;
    y = fmaf(-e1, k1y, yn); y = fmaf(-e2, k2y, y); y += by;
  }
  dc[(size_t)cid * 128 + lane] = z;
  dc[(size_t)cid * 128 + 64 + lane] = y;
}

// sequential chunk combine: h <- M_c h + d_c, store h at chunk starts
__global__ __launch_bounds__(256) void scanB2(
    const float* __restrict__ Mc, const float* __restrict__ dc,
    float* __restrict__ hstart) {
  const int b = blockIdx.x;
  const int tid = threadIdx.x;
  const int i = tid & 127, jh = tid >> 7;
  __shared__ float h[128];
  __shared__ float red[2][128];
  if (tid < 128) h[tid] = 0.f;
  __syncthreads();
  float mreg[64];
  {
    const float* M0 = Mc + (size_t)(b * CH) * 16384;
#pragma unroll
    for (int j = 0; j < 64; ++j) mreg[j] = M0[(size_t)(jh * 64 + j) * 128 + i];
  }
  for (int c = 0; c < CH; ++c) {
    if (tid < 128) hstart[(size_t)(b * CH + c) * 128 + tid] = h[tid];
    float acc = 0.f;
#pragma unroll
    for (int j = 0; j < 64; ++j) acc = fmaf(mreg[j], h[jh * 64 + j], acc);
    red[jh][i] = acc;
    if (c + 1 < CH) {
      const float* Mn = Mc + (size_t)(b * CH + c + 1) * 16384;
#pragma unroll
      for (int j = 0; j < 64; ++j) mreg[j] = Mn[(size_t)(jh * 64 + j) * 128 + i];
    }
    __syncthreads();
    if (tid < 128)
      h[tid] = red[0][tid] + red[1][tid] + dc[(size_t)(b * CH + c) * 128 + tid];
    __syncthreads();
  }
}

// replay within chunk from h_start, one wave per chunk, write hs
__global__ __launch_bounds__(64) void scanB3(
    const float* __restrict__ Feat, const float* __restrict__ hstart,
    float* __restrict__ hs) {
  const int cid = blockIdx.x;
  const int lane = threadIdx.x;
  float z = hstart[(size_t)cid * 128 + lane];
  float y = hstart[(size_t)cid * 128 + 64 + lane];
  const int t0 = (cid >> 5) * TT + (cid & 31) * LCH;
  for (int t = t0; t < t0 + LCH; ++t) {
    const float* __restrict__ f = Feat + (size_t)t * FS;
    float s = f[lane], c1 = f[448 + lane];
    float k1z = f[64 + lane], k1y = f[128 + lane];
    float k2z = f[192 + lane], k2y = f[256 + lane];
    float bz = f[320 + lane], by = f[384 + lane];
    float b1 = f[512], b2 = f[513], c12 = f[514];
    float sz = s * z;
    float zn = fmaf(-c1, y, sz);
    float yn = fmaf(s, y, 0.1f * sz);
    float p = fmaf(k1y, yn, k1z * zn);
    float qq = fmaf(k2y, yn, k2z * zn);
#pragma unroll
    for (int off = 32; off > 0; off >>= 1) {
      p += __shfl_xor(p, off, 64);
      qq += __shfl_xor(qq, off, 64);
    }
    float e1 = b1 * p;
    float d2 = fmaf(-c12, e1, qq);
    float e2 = b2 * d2;
    zn = fmaf(-e1, k1z, zn); zn = fmaf(-e2, k2z, zn); zn += bz;
    yn = fmaf(-e1, k1y, yn); yn = fmaf(-e2, k2y, yn); yn += by;
    hs[(size_t)t * 128 + lane] = zn;
    hs[(size_t)t * 128 + 64 + lane] = yn;
    z = zn; y = yn;
  }
}

// out = hs @ C^T + u*D : tile 64 tokens x 64 dims, K=128 in 2 halves,
// direct-copy tiles via CmT[n][d], k4 inner loop.
__global__ __launch_bounds__(256) void gemmC(
    const float* __restrict__ hs, const float* __restrict__ CmT,
    const float* __restrict__ u, const float* __restrict__ Dv,
    float* __restrict__ out) {
  __shared__ float as2[64][68];   // [token][k-half]
  __shared__ float bs[64][68];    // [k][dim]
  const int tid = threadIdx.x;
  const int tx = tid & 15, ty = tid >> 4;
  const int t0 = blockIdx.x * 64;
  const int d0 = blockIdx.y * 64;
  float acc[4][4];
#pragma unroll
  for (int i = 0; i < 4; ++i)
#pragma unroll
    for (int j = 0; j < 4; ++j) acc[i][j] = 0.f;

  for (int kb = 0; kb < 128; kb += 64) {
#pragma unroll
    for (int l = 0; l < 4; ++l) {
      int idx = tid + l * 256;
      int r = idx >> 4, c4 = (idx & 15) * 4;
      float4 v = *(const float4*)(hs + (size_t)(t0 + r) * 128 + kb + c4);
      *(float4*)&as2[r][c4] = v;
      float4 w = *(const float4*)(CmT + (size_t)(kb + r) * DM + d0 + c4);
      *(float4*)&bs[r][c4] = w;
    }
    __syncthreads();
#pragma unroll
    for (int k4 = 0; k4 < 16; ++k4) {
      float4 bq0 = *(const float4*)&bs[4 * k4 + 0][tx * 4];
      float4 bq1 = *(const float4*)&bs[4 * k4 + 1][tx * 4];
      float4 bq2 = *(const float4*)&bs[4 * k4 + 2][tx * 4];
      float4 bq3 = *(const float4*)&bs[4 * k4 + 3][tx * 4];
#pragma unroll
      for (int i = 0; i < 4; ++i) {
        float4 a = *(const float4*)&as2[ty * 4 + i][4 * k4];
        acc[i][0] = fmaf(a.x, bq0.x, acc[i][0]);
        acc[i][1] = fmaf(a.x, bq0.y, acc[i][1]);
        acc[i][2] = fmaf(a.x, bq0.z, acc[i][2]);
        acc[i][3] = fmaf(a.x, bq0.w, acc[i][3]);
        acc[i][0] = fmaf(a.y, bq1.x, acc[i][0]);
        acc[i][1] = fmaf(a.y, bq1.y, acc[i][1]);
        acc[i][2] = fmaf(a.y, bq1.z, acc[i][2]);
        acc[i][3] = fmaf(a.y, bq1.w, acc[i][3]);
        acc[i][0] = fmaf(a.z, bq2.x, acc[i][0]);
        acc[i][1] = fmaf(a.z, bq2.y, acc[i][1]);
        acc[i][2] = fmaf(a.z, bq2.z, acc[i][2]);
        acc[i][3] = fmaf(a.z, bq2.w, acc[i][3]);
        acc[i][0] = fmaf(a.w, bq3.x, acc[i][0]);
        acc[i][1] = fmaf(a.w, bq3.y, acc[i][1]);
        acc[i][2] = fmaf(a.w, bq3.z, acc[i][2]);
        acc[i][3] = fmaf(a.w, bq3.w, acc[i][3]);
      }
    }
    __syncthreads();
  }
#pragma unroll
  for (int i = 0; i < 4; ++i) {
    int row = t0 + ty * 4 + i;
    float4 uv = *(const float4*)(u + (size_t)row * DM + d0 + tx * 4);
    float4 dv = *(const float4*)(Dv + d0 + tx * 4);
    float4 o;
    o.x = fmaf(uv.x, dv.x, acc[i][0]);
    o.y = fmaf(uv.y, dv.y, acc[i][1]);
    o.z = fmaf(uv.z, dv.z, acc[i][2]);
    o.w = fmaf(uv.w, dv.w, acc[i][3]);
    *(float4*)(out + (size_t)row * DM + d0 + tx * 4) = o;
  }
}

extern "C" void kernel_launch(void* const* d_in, const int* in_sizes, int n_in,
                              void* d_out, int out_size, void* d_ws, size_t ws_size,
                              hipStream_t stream) {
  const float* u      = (const float*)d_in[0];
  const float* W_A    = (const float*)d_in[1];
  const float* b_A    = (const float*)d_in[2];
  const float* W_k    = (const float*)d_in[3];
  const float* b_k    = (const float*)d_in[4];
  const float* W_beta = (const float*)d_in[5];
  const float* b_beta = (const float*)d_in[6];
  const float* B_w    = (const float*)d_in[7];
  const float* B_b    = (const float*)d_in[8];
  const float* Cm     = (const float*)d_in[9];
  const float* Dv     = (const float*)d_in[10];
  float* out = (float*)d_out;
  char* ws = (char*)d_ws;
  // workspace carve-up (~63.7 MB)
  float* Wp     = (float*)(ws);                 // 448*1024*4  = 1,835,008
  float* WpT    = (float*)(ws + 1835008);       // 1024*448*4  = 1,835,008
  float* CmT    = (float*)(ws + 3670016);       // 128*1024*4  =   524,288
  float* bias   = (float*)(ws + 4194304);       // 450*4 (pad 4096)
  float* Feat   = (float*)(ws + 4198400);       // 16384*520*4 = 34,078,720
  float* Mc     = (float*)(ws + 38277120);      // 256*128*128*4 = 16,777,216
  float* dcv    = (float*)(ws + 55054336);      // 131,072
  float* hstart = (float*)(ws + 55185408);      // 131,072
  float* hsb    = (float*)(ws + 55316480);      // 16384*128*4 = 8,388,608

  packW<<<dim3(448), dim3(256), 0, stream>>>(W_A, b_A, W_k, b_k, b_beta,
                                             B_w, B_b, Wp, bias);
  transK<<<dim3(7, 16), dim3(256), 0, stream>>>(Wp, WpT, NW, DM);
  transK<<<dim3(16, 2), dim3(256), 0, stream>>>(Cm, CmT, DM, 128);
  gemmA<<<dim3(128, 7), dim3(256), 0, stream>>>(u, WpT, Feat);
  postA<<<dim3(16384), dim3(64), 0, stream>>>(Feat, bias, u, W_beta);
  scanB1<<<dim3(256), dim3(512), 0, stream>>>(Feat, Mc);
  scanB0<<<dim3(256), dim3(64), 0, stream>>>(Feat, dcv);
  scanB2<<<dim3(8), dim3(256), 0, stream>>>(Mc, dcv, hstart);
  scanB3<<<dim3(256), dim3(64), 0, stream>>>(Feat, hstart, hsb);
  gemmC<<<dim3(256, 16), dim3(256), 0, stream>>>(hsb, CmT, u, Dv, out);
}